// Round 3
// baseline (684.703 us; speedup 1.0000x reference)
//
#include <hip/hip_runtime.h>
#include <hip/hip_cooperative_groups.h>
#include <math.h>

namespace cg = cooperative_groups;

#define F4(p)  (*reinterpret_cast<float4*>(p))
#define CF4(p) (*reinterpret_cast<const float4*>(p))
#define CF2(p) (*reinterpret_cast<const float2*>(p))

struct Params {
    const float *state, *til, *keys, *vals, *rpe;
    const int *step;
    const float *W_state, *b_state, *Wcq1, *bcq1, *Wcq2, *bcq2, *Wq, *bq;
    const float *Wagg, *bagg, *Wrk1, *brk1, *Wrk2, *brk2, *Wrv1, *brv1, *Wrv2, *brv2;
    float *out;
    float *q2buf, *P4, *sc, *Ppv, *P5, *P6, *P7;
};

// 64x64 output tile GEMM, A assembled as bias + sum of NS partial slices.
// A_eff[m, kg] = (bias?bias[kg]:0) + sum_{s<NS} Asrc[(s*64+m)*srcld + kg]
__device__ __forceinline__ void gemm_tile64(
    float* As, float* Ws, const float* Asrc, const float* bias,
    int NS, int srcld, int kc, int k0,
    const float* W, int ldw, int n0,
    float* Pout, int ldo)
{
    const int t = threadIdx.x;
    const int tx = t & 15, ty = t >> 4;
    const int row = t >> 2, kq = (t & 3) * 4;
    const int wrow = t >> 4, wcol = (t & 15) * 4;
    float acc[4][4] = {};
    for (int kk = 0; kk < kc; kk += 16) {
        const int kg = k0 + kk + kq;
        float4 av = {0.f, 0.f, 0.f, 0.f};
        if (bias) av = CF4(&bias[kg]);
        for (int s = 0; s < NS; ++s) {
            float4 v = CF4(&Asrc[(size_t)(s * 64 + row) * srcld + kg]);
            av.x += v.x; av.y += v.y; av.z += v.z; av.w += v.w;
        }
        As[(kq+0)*64+row] = av.x; As[(kq+1)*64+row] = av.y;
        As[(kq+2)*64+row] = av.z; As[(kq+3)*64+row] = av.w;
        F4(&Ws[wrow*64 + wcol]) = CF4(&W[(size_t)(k0 + kk + wrow) * ldw + n0 + wcol]);
        __syncthreads();
        #pragma unroll
        for (int k = 0; k < 16; ++k) {
            float4 a4 = CF4(&As[k*64 + ty*4]);
            float4 w4 = CF4(&Ws[k*64 + tx*4]);
            float a[4] = {a4.x, a4.y, a4.z, a4.w};
            float w[4] = {w4.x, w4.y, w4.z, w4.w};
            #pragma unroll
            for (int i = 0; i < 4; ++i)
                #pragma unroll
                for (int j = 0; j < 4; ++j)
                    acc[i][j] += a[i] * w[j];
        }
        __syncthreads();
    }
    #pragma unroll
    for (int i = 0; i < 4; ++i) {
        float4 o = {acc[i][0], acc[i][1], acc[i][2], acc[i][3]};
        F4(&Pout[(size_t)(ty*4 + i) * ldo + n0 + tx*4]) = o;
    }
}

__global__ __launch_bounds__(256, 2) void dnd_fused(Params p) {
    __shared__ __align__(16) float smem[4352];
    cg::grid_group grid = cg::this_grid();
    const int bid = blockIdx.x;
    const int t = threadIdx.x;

    // ======== Phase A: per-b query chain q2 = ((cat(se,til))@Wcq1+b)@Wcq2+b ========
    if (bid < 64) {
        const int b = bid;
        float* s_in = smem;          // 512
        float* s_u  = smem + 512;    // 512
        float* s_q1 = smem + 1024;   // 512
        s_in[t]       = p.state[b*512 + t];
        s_in[t + 256] = p.state[b*512 + t + 256];
        __syncthreads();
        if (t < 128) {               // se cols 2t, 2t+1
            float a0 = p.b_state[2*t], a1 = p.b_state[2*t+1];
            #pragma unroll 4
            for (int k = 0; k < 512; ++k) {
                float2 w = CF2(&p.W_state[k*256 + 2*t]);
                float s = s_in[k];
                a0 += s * w.x; a1 += s * w.y;
            }
            s_u[2*t] = a0; s_u[2*t+1] = a1;
        } else {                     // til into upper half
            int i = (t - 128) * 2;
            s_u[256 + i]     = p.til[b*256 + i];
            s_u[256 + i + 1] = p.til[b*256 + i + 1];
        }
        __syncthreads();
        {                            // q1 cols 2t, 2t+1
            float a0 = p.bcq1[2*t], a1 = p.bcq1[2*t+1];
            #pragma unroll 4
            for (int k = 0; k < 512; ++k) {
                float2 w = CF2(&p.Wcq1[k*512 + 2*t]);
                float s = s_u[k];
                a0 += s * w.x; a1 += s * w.y;
            }
            s_q1[2*t] = a0; s_q1[2*t+1] = a1;
        }
        __syncthreads();
        {                            // q2 cols 2t, 2t+1 -> global
            float a0 = p.bcq2[2*t], a1 = p.bcq2[2*t+1];
            #pragma unroll 4
            for (int k = 0; k < 512; ++k) {
                float2 w = CF2(&p.Wcq2[k*512 + 2*t]);
                float s = s_q1[k];
                a0 += s * w.x; a1 += s * w.y;
            }
            p.q2buf[b*512 + 2*t]   = a0;
            p.q2buf[b*512 + 2*t+1] = a1;
        }
    }
    grid.sync();

    // ======== Phase B: P4[s] = q2 @ Wq (k-slice s), 64nt x 4ks ========
    if (bid < 256) {
        const int nt = bid & 63, s = bid >> 6;
        gemm_tile64(smem, smem + 1024, p.q2buf, nullptr, 1, 512, 128, s*128,
                    p.Wq, 4096, nt*64, p.P4 + (size_t)s*64*4096, 4096);
    }
    grid.sync();

    // ======== Phase C: scores[b,l,h] (b = bid>>3, l-chunk of 128) ========
    {
        const int b = bid >> 3, lc = bid & 7;
        const int sb = p.step[b];
        const int l0 = lc * 128;
        if (l0 < sb) {
            float* s_q = smem;       // 4096 floats
            for (int i = t; i < 1024; i += 256) {
                float4 v = CF4(&p.bq[i*4]);
                #pragma unroll
                for (int s = 0; s < 4; ++s) {
                    float4 u = CF4(&p.P4[(size_t)(s*64 + b)*4096 + i*4]);
                    v.x += u.x; v.y += u.y; v.z += u.z; v.w += u.w;
                }
                F4(&s_q[i*4]) = v;
            }
            __syncthreads();
            const int lane = t & 63, w = t >> 6;
            float qr[8][8];
            #pragma unroll
            for (int h = 0; h < 8; ++h) {
                float4 x = CF4(&s_q[h*512 + lane*8]);
                float4 y = CF4(&s_q[h*512 + lane*8 + 4]);
                qr[h][0]=x.x; qr[h][1]=x.y; qr[h][2]=x.z; qr[h][3]=x.w;
                qr[h][4]=y.x; qr[h][5]=y.y; qr[h][6]=y.z; qr[h][7]=y.w;
            }
            const int lend = min(l0 + 128, sb);
            const float inv_sqrtK = 0.04419417382415922f;
            const bool p0 = lane & 1, p1 = lane & 2, p2 = lane & 4;
            for (int l = l0 + w; l < lend; l += 4) {
                const float* kp = p.keys + ((size_t)l * 64 + b) * 512 + lane * 8;
                float4 kx = CF4(kp);
                float4 ky = CF4(kp + 4);
                float kv[8] = {kx.x,kx.y,kx.z,kx.w, ky.x,ky.y,ky.z,ky.w};
                float pr[8] = {};
                #pragma unroll
                for (int h = 0; h < 8; ++h)
                    #pragma unroll
                    for (int j = 0; j < 8; ++j)
                        pr[h] += kv[j] * qr[h][j];
                float w4[4], x2[2], y;
                #pragma unroll
                for (int i = 0; i < 4; ++i) {
                    float keep = p0 ? pr[2*i+1] : pr[2*i];
                    float send = p0 ? pr[2*i]   : pr[2*i+1];
                    w4[i] = keep + __shfl_xor(send, 1);
                }
                #pragma unroll
                for (int i = 0; i < 2; ++i) {
                    float keep = p1 ? w4[2*i+1] : w4[2*i];
                    float send = p1 ? w4[2*i]   : w4[2*i+1];
                    x2[i] = keep + __shfl_xor(send, 2);
                }
                {
                    float keep = p2 ? x2[1] : x2[0];
                    float send = p2 ? x2[0] : x2[1];
                    y = keep + __shfl_xor(send, 4);
                }
                y += __shfl_xor(y, 8);
                y += __shfl_xor(y, 16);
                y += __shfl_xor(y, 32);
                if (lane < 8) {
                    float rp = p.rpe[l * 64 + b] * inv_sqrtK;
                    p.sc[((size_t)b * 1024 + l) * 8 + lane] = y * rp;
                }
            }
        }
    }
    grid.sync();

    // ======== Phase D: softmax over valid l per (b,h) ========
    {
        const int b = bid >> 3, h = bid & 7;
        const int sb = p.step[b];
        float* redm = smem;
        float* reds = smem + 8;
        float sv[4];
        float m = -1e30f;
        #pragma unroll
        for (int i = 0; i < 4; ++i) {
            int l = t + i*256;
            if (l < sb) { sv[i] = p.sc[((size_t)b*1024 + l)*8 + h]; m = fmaxf(m, sv[i]); }
            else sv[i] = -1e30f;
        }
        #pragma unroll
        for (int mask = 32; mask; mask >>= 1) m = fmaxf(m, __shfl_xor(m, mask));
        if ((t & 63) == 0) redm[t >> 6] = m;
        __syncthreads();
        m = fmaxf(fmaxf(redm[0], redm[1]), fmaxf(redm[2], redm[3]));
        float s = 0.f;
        #pragma unroll
        for (int i = 0; i < 4; ++i) {
            int l = t + i*256;
            if (l < sb) { float e = expf(sv[i] - m); sv[i] = e; s += e; }
        }
        #pragma unroll
        for (int mask = 32; mask; mask >>= 1) s += __shfl_xor(s, mask);
        if ((t & 63) == 0) reds[t >> 6] = s;
        __syncthreads();
        s = reds[0] + reds[1] + reds[2] + reds[3];
        float inv = 1.f / s;
        #pragma unroll
        for (int i = 0; i < 4; ++i) {
            int l = t + i*256;
            if (l < sb) p.sc[((size_t)b*1024 + l)*8 + h] = sv[i] * inv;
        }
    }
    grid.sync();

    // ======== Phase E: Ppv[lc][b][h*512+v] = sum_l prob*vals (chunk lc) ========
    {
        const int b = bid >> 3, lc = bid & 7;
        const int sb = p.step[b];
        const int l0 = lc * 128;
        float acc[8][2] = {};
        if (l0 < sb) {
            float* p_lds = smem;     // 1024 floats
            const int nl = min(128, sb - l0);
            for (int i = t; i < nl*8; i += 256)
                p_lds[i] = p.sc[((size_t)b*1024 + l0)*8 + i];
            __syncthreads();
            for (int il = 0; il < nl; ++il) {
                const float* vp = p.vals + (((size_t)(l0 + il))*64 + b)*512;
                float va = vp[t];
                float vb = vp[t + 256];
                float4 pa = CF4(&p_lds[il*8]);
                float4 pb = CF4(&p_lds[il*8 + 4]);
                acc[0][0] += pa.x*va; acc[0][1] += pa.x*vb;
                acc[1][0] += pa.y*va; acc[1][1] += pa.y*vb;
                acc[2][0] += pa.z*va; acc[2][1] += pa.z*vb;
                acc[3][0] += pa.w*va; acc[3][1] += pa.w*vb;
                acc[4][0] += pb.x*va; acc[4][1] += pb.x*vb;
                acc[5][0] += pb.y*va; acc[5][1] += pb.y*vb;
                acc[6][0] += pb.z*va; acc[6][1] += pb.z*vb;
                acc[7][0] += pb.w*va; acc[7][1] += pb.w*vb;
            }
        }
        float* pout = p.Ppv + ((size_t)(lc*64) + b)*4096;
        #pragma unroll
        for (int hh = 0; hh < 8; ++hh) {
            pout[hh*512 + t]       = acc[hh][0];
            pout[hh*512 + t + 256] = acc[hh][1];
        }
    }
    grid.sync();

    // ======== Phase F: P5[ks] = (sum8 Ppv) @ Wagg (8nt x 32ks, kc=128) ========
    if (bid < 256) {
        const int nt = bid & 7, ks = bid >> 3;
        gemm_tile64(smem, smem + 1024, p.Ppv, nullptr, 8, 4096, 128, ks*128,
                    p.Wagg, 512, nt*64, p.P5 + (size_t)ks*64*512, 512);
    }
    grid.sync();

    // ======== Phase G: P6[z][ks] = (bagg + sum32 P5) @ {Wrk1|Wrv1} ========
    if (bid < 64) {
        const int z = bid >> 5, r = bid & 31;
        const int nt = r & 7, ks = r >> 3;
        gemm_tile64(smem, smem + 1024, p.P5, p.bagg, 32, 512, 128, ks*128,
                    z ? p.Wrv1 : p.Wrk1, 512, nt*64,
                    p.P6 + (size_t)(z*4 + ks)*64*512, 512);
    }
    grid.sync();

    // ======== Phase H: P7[z][ks] = (b1 + sum4 P6[z]) @ {Wrk2|Wrv2} ========
    if (bid < 64) {
        const int z = bid >> 5, r = bid & 31;
        const int nt = r & 7, ks = r >> 3;
        gemm_tile64(smem, smem + 1024, p.P6 + (size_t)z*4*64*512,
                    z ? p.brv1 : p.brk1, 4, 512, 128, ks*128,
                    z ? p.Wrv2 : p.Wrk2, 512, nt*64,
                    p.P7 + (size_t)(z*4 + ks)*64*512, 512);
    }
    grid.sync();

    // ======== Phase I: out = bias + sum4 P7 ========
    if (bid < 64) {
        int f = bid * 256 + t;           // f4 index in [0, 16384)
        int z = f >> 13, r = f & 8191;
        int m = r >> 7, c4 = (r & 127) * 4;
        const float* bias = z ? p.brv2 : p.brk2;
        float4 a = CF4(&bias[c4]);
        #pragma unroll
        for (int s = 0; s < 4; ++s) {
            float4 v = CF4(&p.P7[((size_t)(z*4 + s)*64 + m)*512 + c4]);
            a.x += v.x; a.y += v.y; a.z += v.z; a.w += v.w;
        }
        F4(&p.out[((size_t)z*64 + m)*512 + c4]) = a;
    }
}

extern "C" void kernel_launch(void* const* d_in, const int* in_sizes, int n_in,
                              void* d_out, int out_size, void* d_ws, size_t ws_size,
                              hipStream_t stream) {
    float* ws = (float*)d_ws;
    Params prm;
    prm.state   = (const float*)d_in[0];
    prm.til     = (const float*)d_in[1];
    prm.keys    = (const float*)d_in[2];
    prm.vals    = (const float*)d_in[3];
    prm.rpe     = (const float*)d_in[4];
    prm.step    = (const int*)d_in[5];
    prm.W_state = (const float*)d_in[6];
    prm.b_state = (const float*)d_in[7];
    prm.Wcq1 = (const float*)d_in[8];
    prm.bcq1 = (const float*)d_in[9];
    prm.Wcq2 = (const float*)d_in[10];
    prm.bcq2 = (const float*)d_in[11];
    prm.Wq   = (const float*)d_in[12];
    prm.bq   = (const float*)d_in[13];
    prm.Wagg = (const float*)d_in[14];
    prm.bagg = (const float*)d_in[15];
    prm.Wrk1 = (const float*)d_in[16];
    prm.brk1 = (const float*)d_in[17];
    prm.Wrk2 = (const float*)d_in[18];
    prm.brk2 = (const float*)d_in[19];
    prm.Wrv1 = (const float*)d_in[20];
    prm.brv1 = (const float*)d_in[21];
    prm.Wrv2 = (const float*)d_in[22];
    prm.brv2 = (const float*)d_in[23];
    prm.out  = (float*)d_out;
    prm.q2buf = ws;                 // 32768
    prm.P4    = ws + 32768;         // 4*64*4096  = 1048576
    prm.sc    = ws + 1081344;       // 64*1024*8  = 524288
    prm.Ppv   = ws + 1605632;       // 8*64*4096  = 2097152
    prm.P5    = ws + 3702784;       // 32*64*512  = 1048576
    prm.P6    = ws + 4751360;       // 2*4*64*512 = 262144
    prm.P7    = ws + 5013504;       // 2*4*64*512 = 262144

    void* args[] = {&prm};
    hipLaunchCooperativeKernel((const void*)dnd_fused, dim3(512), dim3(256),
                               args, 0, stream);
}

// Round 4
// 236.589 us; speedup vs baseline: 2.8941x; 2.8941x over previous
//
#include <hip/hip_runtime.h>
#include <math.h>

#define F4(p)  (*reinterpret_cast<float4*>(p))
#define CF4(p) (*reinterpret_cast<const float4*>(p))
#define CF2(p) (*reinterpret_cast<const float2*>(p))

// ============ k1: per-b query chain, 1024 threads, k-split across waves ============
__global__ __launch_bounds__(1024) void k_qchain(
    const float* __restrict__ state, const float* __restrict__ til,
    const float* __restrict__ W_state, const float* __restrict__ b_state,
    const float* __restrict__ Wcq1, const float* __restrict__ bcq1,
    const float* __restrict__ Wcq2, const float* __restrict__ bcq2,
    float* __restrict__ q2buf)
{
    __shared__ float s_in[512], s_u[512], s_q1[512];
    __shared__ float2 part[1024];
    const int b = blockIdx.x, t = threadIdx.x;
    if (t < 512) s_in[t] = state[b*512 + t];
    __syncthreads();
    // mv1: u[0:256] = b_state + state @ W_state ; 128 col-pairs x 8 k-slices
    {
        const int c = t & 127, kq = t >> 7;       // col2 = 2c, k in [kq*64, kq*64+64)
        float2 a = {0.f, 0.f};
        #pragma unroll 8
        for (int k = kq*64; k < kq*64 + 64; ++k) {
            float s = s_in[k];
            float2 w = CF2(&W_state[k*256 + c*2]);
            a.x += s * w.x; a.y += s * w.y;
        }
        part[t] = a;
    }
    __syncthreads();
    if (t < 128) {
        float2 r = CF2(&b_state[t*2]);
        #pragma unroll
        for (int s = 0; s < 8; ++s) { r.x += part[s*128 + t].x; r.y += part[s*128 + t].y; }
        s_u[t*2] = r.x; s_u[t*2+1] = r.y;
    } else if (t < 256) {
        int i = (t - 128) * 2;
        float2 v = CF2(&til[b*256 + i]);
        s_u[256 + i] = v.x; s_u[256 + i + 1] = v.y;
    }
    __syncthreads();
    // mv2: q1 = bcq1 + u @ Wcq1 ; 256 col-pairs x 4 k-slices
    {
        const int c = t & 255, kq = t >> 8;
        float2 a = {0.f, 0.f};
        #pragma unroll 8
        for (int k = kq*128; k < kq*128 + 128; ++k) {
            float s = s_u[k];
            float2 w = CF2(&Wcq1[k*512 + c*2]);
            a.x += s * w.x; a.y += s * w.y;
        }
        part[t] = a;
    }
    __syncthreads();
    if (t < 256) {
        float2 r = CF2(&bcq1[t*2]);
        #pragma unroll
        for (int s = 0; s < 4; ++s) { r.x += part[s*256 + t].x; r.y += part[s*256 + t].y; }
        s_q1[t*2] = r.x; s_q1[t*2+1] = r.y;
    }
    __syncthreads();
    // mv3: q2 = bcq2 + q1 @ Wcq2
    {
        const int c = t & 255, kq = t >> 8;
        float2 a = {0.f, 0.f};
        #pragma unroll 8
        for (int k = kq*128; k < kq*128 + 128; ++k) {
            float s = s_q1[k];
            float2 w = CF2(&Wcq2[k*512 + c*2]);
            a.x += s * w.x; a.y += s * w.y;
        }
        part[t] = a;
    }
    __syncthreads();
    if (t < 256) {
        float2 r = CF2(&bcq2[t*2]);
        #pragma unroll
        for (int s = 0; s < 4; ++s) { r.x += part[s*256 + t].x; r.y += part[s*256 + t].y; }
        q2buf[b*512 + t*2]   = r.x;
        q2buf[b*512 + t*2+1] = r.y;
    }
}

// ============ shared 64x64-tile GEMM core (256 threads) ============
// A_eff[m,kg] = (inbias?inbias[kg]:0) + sum_{s<NS} Asrc[(s*64+m)*srcld+kg]
// Pout[m, n0+n] = acc[m,n] + (obias?obias[n0+n]:0)
__device__ __forceinline__ void gemm_core(
    const float* __restrict__ Asrc, const float* __restrict__ inbias,
    int NS, int srcld, int kc, int k0,
    const float* __restrict__ W, int ldw, int n0,
    const float* __restrict__ obias, float* __restrict__ Pout, int ldo)
{
    __shared__ float As[16*64], Ws[16*64];
    const int t = threadIdx.x;
    const int tx = t & 15, ty = t >> 4;
    const int row = t >> 2, kq = (t & 3) * 4;
    const int wrow = t >> 4, wcol = (t & 15) * 4;
    float acc[4][4] = {};
    for (int kk = 0; kk < kc; kk += 16) {
        const int kg = k0 + kk + kq;
        float4 av = {0.f, 0.f, 0.f, 0.f};
        if (inbias) av = CF4(&inbias[kg]);
        for (int s = 0; s < NS; ++s) {
            float4 v = CF4(&Asrc[(size_t)(s*64 + row)*srcld + kg]);
            av.x += v.x; av.y += v.y; av.z += v.z; av.w += v.w;
        }
        As[(kq+0)*64+row] = av.x; As[(kq+1)*64+row] = av.y;
        As[(kq+2)*64+row] = av.z; As[(kq+3)*64+row] = av.w;
        F4(&Ws[wrow*64 + wcol]) = CF4(&W[(size_t)(k0 + kk + wrow)*ldw + n0 + wcol]);
        __syncthreads();
        #pragma unroll
        for (int k = 0; k < 16; ++k) {
            float4 a4 = CF4(&As[k*64 + ty*4]);
            float4 w4 = CF4(&Ws[k*64 + tx*4]);
            float a[4] = {a4.x, a4.y, a4.z, a4.w};
            float w[4] = {w4.x, w4.y, w4.z, w4.w};
            #pragma unroll
            for (int i = 0; i < 4; ++i)
                #pragma unroll
                for (int j = 0; j < 4; ++j)
                    acc[i][j] += a[i] * w[j];
        }
        __syncthreads();
    }
    #pragma unroll
    for (int i = 0; i < 4; ++i) {
        float4 o = {acc[i][0], acc[i][1], acc[i][2], acc[i][3]};
        if (obias) {
            float4 ob = CF4(&obias[n0 + tx*4]);
            o.x += ob.x; o.y += ob.y; o.z += ob.z; o.w += ob.w;
        }
        F4(&Pout[(size_t)(ty*4 + i)*ldo + n0 + tx*4]) = o;
    }
}

// ============ k2: qh = q2 @ Wq + bq, full-K, 64 tiles ============
__global__ __launch_bounds__(256) void k_qh(
    const float* __restrict__ q2buf, const float* __restrict__ Wq,
    const float* __restrict__ bq, float* __restrict__ qh)
{
    gemm_core(q2buf, nullptr, 1, 512, 512, 0, Wq, 4096, blockIdx.x*64, bq, qh, 4096);
}

// ============ k3: scores[b,l,h] ============
__global__ __launch_bounds__(256) void k_scores(
    const float* __restrict__ keys, const float* __restrict__ rpe,
    const float* __restrict__ qh, const int* __restrict__ step,
    float* __restrict__ sc)
{
    const int b = blockIdx.y, lc = blockIdx.x;
    const int sb = step[b];
    const int l0 = lc * 64;
    if (l0 >= sb) return;
    __shared__ float s_q[4096];
    const int t = threadIdx.x;
    for (int i = t; i < 1024; i += 256)
        F4(&s_q[i*4]) = CF4(&qh[(size_t)b*4096 + i*4]);
    __syncthreads();
    const int lane = t & 63, w = t >> 6;
    float qr[8][8];
    #pragma unroll
    for (int h = 0; h < 8; ++h) {
        float4 x = CF4(&s_q[h*512 + lane*8]);
        float4 y = CF4(&s_q[h*512 + lane*8 + 4]);
        qr[h][0]=x.x; qr[h][1]=x.y; qr[h][2]=x.z; qr[h][3]=x.w;
        qr[h][4]=y.x; qr[h][5]=y.y; qr[h][6]=y.z; qr[h][7]=y.w;
    }
    const int lend = min(l0 + 64, sb);
    const float inv_sqrtK = 0.04419417382415922f;
    const bool p0 = lane & 1, p1 = lane & 2, p2 = lane & 4;
    for (int l = l0 + w; l < lend; l += 4) {
        const float* kp = keys + ((size_t)l * 64 + b) * 512 + lane * 8;
        float4 kx = CF4(kp);
        float4 ky = CF4(kp + 4);
        float kv[8] = {kx.x,kx.y,kx.z,kx.w, ky.x,ky.y,ky.z,ky.w};
        float pr[8] = {};
        #pragma unroll
        for (int h = 0; h < 8; ++h)
            #pragma unroll
            for (int j = 0; j < 8; ++j)
                pr[h] += kv[j] * qr[h][j];
        float w4[4], x2[2], y;
        #pragma unroll
        for (int i = 0; i < 4; ++i) {
            float keep = p0 ? pr[2*i+1] : pr[2*i];
            float send = p0 ? pr[2*i]   : pr[2*i+1];
            w4[i] = keep + __shfl_xor(send, 1);
        }
        #pragma unroll
        for (int i = 0; i < 2; ++i) {
            float keep = p1 ? w4[2*i+1] : w4[2*i];
            float send = p1 ? w4[2*i]   : w4[2*i+1];
            x2[i] = keep + __shfl_xor(send, 2);
        }
        {
            float keep = p2 ? x2[1] : x2[0];
            float send = p2 ? x2[0] : x2[1];
            y = keep + __shfl_xor(send, 4);
        }
        y += __shfl_xor(y, 8);
        y += __shfl_xor(y, 16);
        y += __shfl_xor(y, 32);
        if (lane < 8) {
            float rp = rpe[l * 64 + b] * inv_sqrtK;
            sc[((size_t)b * 1024 + l) * 8 + lane] = y * rp;
        }
    }
}

// ============ k4: fused softmax + PV, writes Ppv[lc][b][h*512+v] ============
__global__ __launch_bounds__(256) void k_softpv(
    const float* __restrict__ vals, const float* __restrict__ sc,
    const int* __restrict__ step, float* __restrict__ Ppv)
{
    __shared__ float p[8192];          // prob[l][h]
    __shared__ float red[256], maxh[8], invh[8];
    const int b = blockIdx.y, lc = blockIdx.x;
    const int sb = step[b];
    const int t = threadIdx.x;
    // stage scores for valid l
    for (int i = t*4; i < sb*8; i += 1024)
        F4(&p[i]) = CF4(&sc[(size_t)b*8192 + i]);
    __syncthreads();
    // per-h max (h = t&7, g = t>>3 strides l by 32)
    const int h = t & 7, g = t >> 3;
    float m = -1e30f;
    for (int l = g; l < sb; l += 32) m = fmaxf(m, p[l*8 + h]);
    red[g*8 + h] = m;
    __syncthreads();
    #pragma unroll
    for (int s = 16; s; s >>= 1) {
        if (g < s) red[g*8+h] = fmaxf(red[g*8+h], red[(g+s)*8+h]);
        __syncthreads();
    }
    if (t < 8) maxh[t] = red[t];
    __syncthreads();
    // exp + per-h sum
    float mh = maxh[h], s_acc = 0.f;
    for (int l = g; l < sb; l += 32) {
        float e = __expf(p[l*8 + h] - mh);
        p[l*8 + h] = e;
        s_acc += e;
    }
    red[g*8 + h] = s_acc;
    __syncthreads();
    #pragma unroll
    for (int s = 16; s; s >>= 1) {
        if (g < s) red[g*8+h] += red[(g+s)*8+h];
        __syncthreads();
    }
    if (t < 8) invh[t] = 1.f / red[t];
    __syncthreads();
    // PV over this block's l-chunk; normalization folded into prob read
    const float4 ivA = {invh[0], invh[1], invh[2], invh[3]};
    const float4 ivB = {invh[4], invh[5], invh[6], invh[7]};
    const int par = t >> 7, c = t & 127;
    const int lbeg = lc * 256;
    const int lend = min(lbeg + 256, sb);
    float4 acc[8] = {};
    for (int il = lbeg + par; il < lend; il += 2) {
        float4 v = CF4(&vals[((size_t)il*64 + b)*512 + c*4]);
        float4 pa = CF4(&p[il*8]);
        float4 pb = CF4(&p[il*8 + 4]);
        pa.x *= ivA.x; pa.y *= ivA.y; pa.z *= ivA.z; pa.w *= ivA.w;
        pb.x *= ivB.x; pb.y *= ivB.y; pb.z *= ivB.z; pb.w *= ivB.w;
        acc[0].x += pa.x*v.x; acc[0].y += pa.x*v.y; acc[0].z += pa.x*v.z; acc[0].w += pa.x*v.w;
        acc[1].x += pa.y*v.x; acc[1].y += pa.y*v.y; acc[1].z += pa.y*v.z; acc[1].w += pa.y*v.w;
        acc[2].x += pa.z*v.x; acc[2].y += pa.z*v.y; acc[2].z += pa.z*v.z; acc[2].w += pa.z*v.w;
        acc[3].x += pa.w*v.x; acc[3].y += pa.w*v.y; acc[3].z += pa.w*v.z; acc[3].w += pa.w*v.w;
        acc[4].x += pb.x*v.x; acc[4].y += pb.x*v.y; acc[4].z += pb.x*v.z; acc[4].w += pb.x*v.w;
        acc[5].x += pb.y*v.x; acc[5].y += pb.y*v.y; acc[5].z += pb.y*v.z; acc[5].w += pb.y*v.w;
        acc[6].x += pb.z*v.x; acc[6].y += pb.z*v.y; acc[6].z += pb.z*v.z; acc[6].w += pb.z*v.w;
        acc[7].x += pb.w*v.x; acc[7].y += pb.w*v.y; acc[7].z += pb.w*v.z; acc[7].w += pb.w*v.w;
    }
    __syncthreads();   // done reading p; reuse for parity combine
    float* comb = p;   // 128 cols x 8 heads x float4 = 16KB
    if (par == 1) {
        #pragma unroll
        for (int hh = 0; hh < 8; ++hh)
            F4(&comb[(c*8 + hh)*4]) = acc[hh];
    }
    __syncthreads();
    if (par == 0) {
        float* pout = Ppv + ((size_t)(lc*64) + b)*4096;
        #pragma unroll
        for (int hh = 0; hh < 8; ++hh) {
            float4 o = CF4(&comb[(c*8 + hh)*4]);
            o.x += acc[hh].x; o.y += acc[hh].y; o.z += acc[hh].z; o.w += acc[hh].w;
            F4(&pout[hh*512 + c*4]) = o;
        }
    }
}

// ============ k5: P5[ks] = (sum4 Ppv) @ Wagg, split-K ============
__global__ __launch_bounds__(256) void k_agg(
    const float* __restrict__ Ppv, const float* __restrict__ Wagg,
    float* __restrict__ P5)
{
    const int nt = blockIdx.x, ks = blockIdx.y;
    gemm_core(Ppv, nullptr, 4, 4096, 128, ks*128, Wagg, 512, nt*64,
              nullptr, P5 + (size_t)ks*64*512, 512);
}

// ============ k6: P6[z][ks] = (bagg + sum32 P5) @ {Wrk1|Wrv1} ============
__global__ __launch_bounds__(256) void k_rkv1(
    const float* __restrict__ P5, const float* __restrict__ bagg,
    const float* __restrict__ Wrk1, const float* __restrict__ Wrv1,
    float* __restrict__ P6)
{
    const int nt = blockIdx.x, ks = blockIdx.y, z = blockIdx.z;
    gemm_core(P5, bagg, 32, 512, 128, ks*128, z ? Wrv1 : Wrk1, 512, nt*64,
              nullptr, P6 + (size_t)(z*4 + ks)*64*512, 512);
}

// ============ k7: out[z] = (b1 + sum4 P6[z]) @ {Wrk2|Wrv2} + b2, full-K ============
__global__ __launch_bounds__(256) void k_rkv2(
    const float* __restrict__ P6,
    const float* __restrict__ brk1, const float* __restrict__ brv1,
    const float* __restrict__ Wrk2, const float* __restrict__ Wrv2,
    const float* __restrict__ brk2, const float* __restrict__ brv2,
    float* __restrict__ out)
{
    const int nt = blockIdx.x, z = blockIdx.z;
    gemm_core(P6 + (size_t)z*4*64*512, z ? brv1 : brk1, 4, 512, 512, 0,
              z ? Wrv2 : Wrk2, 512, nt*64,
              z ? brv2 : brk2, out + (size_t)z*64*512, 512);
}

// ============ launch ============
extern "C" void kernel_launch(void* const* d_in, const int* in_sizes, int n_in,
                              void* d_out, int out_size, void* d_ws, size_t ws_size,
                              hipStream_t stream) {
    const float* state   = (const float*)d_in[0];
    const float* til     = (const float*)d_in[1];
    const float* keys    = (const float*)d_in[2];
    const float* vals    = (const float*)d_in[3];
    const float* rpe     = (const float*)d_in[4];
    const int*   step    = (const int*)d_in[5];
    const float* W_state = (const float*)d_in[6];
    const float* b_state = (const float*)d_in[7];
    const float* Wcq1 = (const float*)d_in[8];
    const float* bcq1 = (const float*)d_in[9];
    const float* Wcq2 = (const float*)d_in[10];
    const float* bcq2 = (const float*)d_in[11];
    const float* Wq   = (const float*)d_in[12];
    const float* bq   = (const float*)d_in[13];
    const float* Wagg = (const float*)d_in[14];
    const float* bagg = (const float*)d_in[15];
    const float* Wrk1 = (const float*)d_in[16];
    const float* brk1 = (const float*)d_in[17];
    const float* Wrk2 = (const float*)d_in[18];
    const float* brk2 = (const float*)d_in[19];
    const float* Wrv1 = (const float*)d_in[20];
    const float* brv1 = (const float*)d_in[21];
    const float* Wrv2 = (const float*)d_in[22];
    const float* brv2 = (const float*)d_in[23];
    float* out = (float*)d_out;
    float* ws  = (float*)d_ws;

    float* q2buf = ws;             // 64*512      = 32768
    float* qh    = ws + 32768;     // 64*4096     = 262144
    float* sc    = ws + 294912;    // 64*1024*8   = 524288
    float* Ppv   = ws + 819200;    // 4*64*4096   = 1048576
    float* P5    = ws + 1867776;   // 32*64*512   = 1048576
    float* P6    = ws + 2916352;   // 2*4*64*512  = 262144

    k_qchain<<<64, 1024, 0, stream>>>(state, til, W_state, b_state,
                                      Wcq1, bcq1, Wcq2, bcq2, q2buf);
    k_qh    <<<64, 256, 0, stream>>>(q2buf, Wq, bq, qh);
    k_scores<<<dim3(16,64), 256, 0, stream>>>(keys, rpe, qh, step, sc);
    k_softpv<<<dim3(4,64),  256, 0, stream>>>(vals, sc, step, Ppv);
    k_agg   <<<dim3(8,32),  256, 0, stream>>>(Ppv, Wagg, P5);
    k_rkv1  <<<dim3(8,4,2), 256, 0, stream>>>(P5, bagg, Wrk1, Wrv1, P6);
    k_rkv2  <<<dim3(8,1,2), 256, 0, stream>>>(P6, brk1, brv1, Wrk2, Wrv2,
                                              brk2, brv2, out);
}

// Round 5
// 227.154 us; speedup vs baseline: 3.0143x; 1.0415x over previous
//
#include <hip/hip_runtime.h>
#include <math.h>

#define F4(p)  (*reinterpret_cast<float4*>(p))
#define CF4(p) (*reinterpret_cast<const float4*>(p))
#define CF2(p) (*reinterpret_cast<const float2*>(p))

// ============ k1: per-b query chain, 1024 threads, k-split across waves ============
__global__ __launch_bounds__(1024) void k_qchain(
    const float* __restrict__ state, const float* __restrict__ til,
    const float* __restrict__ W_state, const float* __restrict__ b_state,
    const float* __restrict__ Wcq1, const float* __restrict__ bcq1,
    const float* __restrict__ Wcq2, const float* __restrict__ bcq2,
    float* __restrict__ q2buf)
{
    __shared__ float s_in[512], s_u[512], s_q1[512];
    __shared__ float2 part[1024];
    const int b = blockIdx.x, t = threadIdx.x;
    if (t < 512) s_in[t] = state[b*512 + t];
    __syncthreads();
    // mv1: u[0:256] = b_state + state @ W_state ; 128 col-pairs x 8 k-slices
    {
        const int c = t & 127, kq = t >> 7;
        float2 a = {0.f, 0.f};
        #pragma unroll 8
        for (int k = kq*64; k < kq*64 + 64; ++k) {
            float s = s_in[k];
            float2 w = CF2(&W_state[k*256 + c*2]);
            a.x += s * w.x; a.y += s * w.y;
        }
        part[t] = a;
    }
    __syncthreads();
    if (t < 128) {
        float2 r = CF2(&b_state[t*2]);
        #pragma unroll
        for (int s = 0; s < 8; ++s) { r.x += part[s*128 + t].x; r.y += part[s*128 + t].y; }
        s_u[t*2] = r.x; s_u[t*2+1] = r.y;
    } else if (t < 256) {
        int i = (t - 128) * 2;
        float2 v = CF2(&til[b*256 + i]);
        s_u[256 + i] = v.x; s_u[256 + i + 1] = v.y;
    }
    __syncthreads();
    // mv2: q1 = bcq1 + u @ Wcq1 ; 256 col-pairs x 4 k-slices
    {
        const int c = t & 255, kq = t >> 8;
        float2 a = {0.f, 0.f};
        #pragma unroll 8
        for (int k = kq*128; k < kq*128 + 128; ++k) {
            float s = s_u[k];
            float2 w = CF2(&Wcq1[k*512 + c*2]);
            a.x += s * w.x; a.y += s * w.y;
        }
        part[t] = a;
    }
    __syncthreads();
    if (t < 256) {
        float2 r = CF2(&bcq1[t*2]);
        #pragma unroll
        for (int s = 0; s < 4; ++s) { r.x += part[s*256 + t].x; r.y += part[s*256 + t].y; }
        s_q1[t*2] = r.x; s_q1[t*2+1] = r.y;
    }
    __syncthreads();
    // mv3: q2 = bcq2 + q1 @ Wcq2
    {
        const int c = t & 255, kq = t >> 8;
        float2 a = {0.f, 0.f};
        #pragma unroll 8
        for (int k = kq*128; k < kq*128 + 128; ++k) {
            float s = s_q1[k];
            float2 w = CF2(&Wcq2[k*512 + c*2]);
            a.x += s * w.x; a.y += s * w.y;
        }
        part[t] = a;
    }
    __syncthreads();
    if (t < 256) {
        float2 r = CF2(&bcq2[t*2]);
        #pragma unroll
        for (int s = 0; s < 4; ++s) { r.x += part[s*256 + t].x; r.y += part[s*256 + t].y; }
        q2buf[b*512 + t*2]   = r.x;
        q2buf[b*512 + t*2+1] = r.y;
    }
}

// ============ shared 64x64-tile GEMM core (256 threads) ============
__device__ __forceinline__ void gemm_core(
    const float* __restrict__ Asrc, const float* __restrict__ inbias,
    int NS, int srcld, int kc, int k0,
    const float* __restrict__ W, int ldw, int n0,
    const float* __restrict__ obias, float* __restrict__ Pout, int ldo)
{
    __shared__ float As[16*64], Ws[16*64];
    const int t = threadIdx.x;
    const int tx = t & 15, ty = t >> 4;
    const int row = t >> 2, kq = (t & 3) * 4;
    const int wrow = t >> 4, wcol = (t & 15) * 4;
    float acc[4][4] = {};
    for (int kk = 0; kk < kc; kk += 16) {
        const int kg = k0 + kk + kq;
        float4 av = {0.f, 0.f, 0.f, 0.f};
        if (inbias) av = CF4(&inbias[kg]);
        for (int s = 0; s < NS; ++s) {
            float4 v = CF4(&Asrc[(size_t)(s*64 + row)*srcld + kg]);
            av.x += v.x; av.y += v.y; av.z += v.z; av.w += v.w;
        }
        As[(kq+0)*64+row] = av.x; As[(kq+1)*64+row] = av.y;
        As[(kq+2)*64+row] = av.z; As[(kq+3)*64+row] = av.w;
        F4(&Ws[wrow*64 + wcol]) = CF4(&W[(size_t)(k0 + kk + wrow)*ldw + n0 + wcol]);
        __syncthreads();
        #pragma unroll
        for (int k = 0; k < 16; ++k) {
            float4 a4 = CF4(&As[k*64 + ty*4]);
            float4 w4 = CF4(&Ws[k*64 + tx*4]);
            float a[4] = {a4.x, a4.y, a4.z, a4.w};
            float w[4] = {w4.x, w4.y, w4.z, w4.w};
            #pragma unroll
            for (int i = 0; i < 4; ++i)
                #pragma unroll
                for (int j = 0; j < 4; ++j)
                    acc[i][j] += a[i] * w[j];
        }
        __syncthreads();
    }
    #pragma unroll
    for (int i = 0; i < 4; ++i) {
        float4 o = {acc[i][0], acc[i][1], acc[i][2], acc[i][3]};
        if (obias) {
            float4 ob = CF4(&obias[n0 + tx*4]);
            o.x += ob.x; o.y += ob.y; o.z += ob.z; o.w += ob.w;
        }
        F4(&Pout[(size_t)(ty*4 + i)*ldo + n0 + tx*4]) = o;
    }
}

// ============ k2: qh = q2 @ Wq + bq, full-K ============
__global__ __launch_bounds__(256) void k_qh(
    const float* __restrict__ q2buf, const float* __restrict__ Wq,
    const float* __restrict__ bq, float* __restrict__ qh)
{
    gemm_core(q2buf, nullptr, 1, 512, 512, 0, Wq, 4096, blockIdx.x*64, bq, qh, 4096);
}

// ============ k3: flash attention chunk: scores+local softmax+PV ============
// Facc[lc][b][h*512+v] = sum_{l in chunk} exp(sc-m_lc) * vals ; Fms[lc][b][h] = (m,s)
__global__ __launch_bounds__(256) void k_fa(
    const float* __restrict__ keys, const float* __restrict__ rpe,
    const float* __restrict__ qh, const float* __restrict__ vals,
    const int* __restrict__ step,
    float* __restrict__ Facc, float* __restrict__ Fms)
{
    __shared__ float s_q[4096];       // q staging; reused for parity combine
    __shared__ float s_sc[128*8];     // chunk scores -> exp
    __shared__ float red[256];
    __shared__ float s_m[8];
    const int b = blockIdx.y, lc = blockIdx.x;
    const int sb = step[b];
    const int l0 = lc * 128;
    const int t = threadIdx.x;
    float* facc_out = Facc + ((size_t)(lc*64) + b)*4096;
    if (l0 >= sb) {
        float4 z = {0.f, 0.f, 0.f, 0.f};
        for (int i = t; i < 1024; i += 256) F4(&facc_out[i*4]) = z;
        if (t < 8) {
            size_t o = ((size_t)(lc*64 + b)*8 + t)*2;
            Fms[o] = -1e30f; Fms[o+1] = 0.f;
        }
        return;
    }
    // stage q[b]
    for (int i = t; i < 1024; i += 256)
        F4(&s_q[i*4]) = CF4(&qh[(size_t)b*4096 + i*4]);
    __syncthreads();
    const int lane = t & 63, w = t >> 6;
    float qr[8][8];
    #pragma unroll
    for (int h = 0; h < 8; ++h) {
        float4 x = CF4(&s_q[h*512 + lane*8]);
        float4 y = CF4(&s_q[h*512 + lane*8 + 4]);
        qr[h][0]=x.x; qr[h][1]=x.y; qr[h][2]=x.z; qr[h][3]=x.w;
        qr[h][4]=y.x; qr[h][5]=y.y; qr[h][6]=y.z; qr[h][7]=y.w;
    }
    const int nl = min(128, sb - l0);
    const float inv_sqrtK = 0.04419417382415922f;
    const bool p0 = lane & 1, p1 = lane & 2, p2 = lane & 4;
    for (int il = w; il < nl; il += 4) {
        const int l = l0 + il;
        const float* kp = keys + ((size_t)l * 64 + b) * 512 + lane * 8;
        float4 kx = CF4(kp);
        float4 ky = CF4(kp + 4);
        float kv[8] = {kx.x,kx.y,kx.z,kx.w, ky.x,ky.y,ky.z,ky.w};
        float pr[8] = {};
        #pragma unroll
        for (int h = 0; h < 8; ++h)
            #pragma unroll
            for (int j = 0; j < 8; ++j)
                pr[h] += kv[j] * qr[h][j];
        float w4[4], x2[2], y;
        #pragma unroll
        for (int i = 0; i < 4; ++i) {
            float keep = p0 ? pr[2*i+1] : pr[2*i];
            float send = p0 ? pr[2*i]   : pr[2*i+1];
            w4[i] = keep + __shfl_xor(send, 1);
        }
        #pragma unroll
        for (int i = 0; i < 2; ++i) {
            float keep = p1 ? w4[2*i+1] : w4[2*i];
            float send = p1 ? w4[2*i]   : w4[2*i+1];
            x2[i] = keep + __shfl_xor(send, 2);
        }
        {
            float keep = p2 ? x2[1] : x2[0];
            float send = p2 ? x2[0] : x2[1];
            y = keep + __shfl_xor(send, 4);
        }
        y += __shfl_xor(y, 8);
        y += __shfl_xor(y, 16);
        y += __shfl_xor(y, 32);
        if (lane < 8)
            s_sc[il*8 + lane] = y * rpe[l * 64 + b] * inv_sqrtK;
    }
    __syncthreads();
    // local softmax stats over nl entries; h = t&7, g = t>>3 (32 groups)
    const int h = t & 7, g = t >> 3;
    float m = -1e30f;
    for (int l = g; l < nl; l += 32) m = fmaxf(m, s_sc[l*8 + h]);
    red[g*8 + h] = m;
    __syncthreads();
    #pragma unroll
    for (int s = 16; s; s >>= 1) {
        if (g < s) red[g*8+h] = fmaxf(red[g*8+h], red[(g+s)*8+h]);
        __syncthreads();
    }
    if (t < 8) s_m[t] = red[t];
    __syncthreads();
    float mh = s_m[h], s_acc = 0.f;
    for (int l = g; l < nl; l += 32) {
        float e = __expf(s_sc[l*8 + h] - mh);
        s_sc[l*8 + h] = e;
        s_acc += e;
    }
    red[g*8 + h] = s_acc;
    __syncthreads();
    #pragma unroll
    for (int s = 16; s; s >>= 1) {
        if (g < s) red[g*8+h] += red[(g+s)*8+h];
        __syncthreads();
    }
    if (t < 8) {
        size_t o = ((size_t)(lc*64 + b)*8 + t)*2;
        Fms[o] = s_m[t]; Fms[o+1] = red[t];
    }
    // PV: unnormalized exp-weighted sum over chunk
    const int par = t >> 7, c = t & 127;
    float4 acc[8] = {};
    for (int il = par; il < nl; il += 2) {
        float4 v = CF4(&vals[((size_t)(l0 + il)*64 + b)*512 + c*4]);
        float4 pa = CF4(&s_sc[il*8]);
        float4 pb = CF4(&s_sc[il*8 + 4]);
        acc[0].x += pa.x*v.x; acc[0].y += pa.x*v.y; acc[0].z += pa.x*v.z; acc[0].w += pa.x*v.w;
        acc[1].x += pa.y*v.x; acc[1].y += pa.y*v.y; acc[1].z += pa.y*v.z; acc[1].w += pa.y*v.w;
        acc[2].x += pa.z*v.x; acc[2].y += pa.z*v.y; acc[2].z += pa.z*v.z; acc[2].w += pa.z*v.w;
        acc[3].x += pa.w*v.x; acc[3].y += pa.w*v.y; acc[3].z += pa.w*v.z; acc[3].w += pa.w*v.w;
        acc[4].x += pb.x*v.x; acc[4].y += pb.x*v.y; acc[4].z += pb.x*v.z; acc[4].w += pb.x*v.w;
        acc[5].x += pb.y*v.x; acc[5].y += pb.y*v.y; acc[5].z += pb.y*v.z; acc[5].w += pb.y*v.w;
        acc[6].x += pb.z*v.x; acc[6].y += pb.z*v.y; acc[6].z += pb.z*v.z; acc[6].w += pb.z*v.w;
        acc[7].x += pb.w*v.x; acc[7].y += pb.w*v.y; acc[7].z += pb.w*v.z; acc[7].w += pb.w*v.w;
    }
    __syncthreads();   // done with s_q and s_sc; reuse s_q for parity combine
    if (par == 1) {
        #pragma unroll
        for (int hh = 0; hh < 8; ++hh)
            F4(&s_q[(c*8 + hh)*4]) = acc[hh];
    }
    __syncthreads();
    if (par == 0) {
        #pragma unroll
        for (int hh = 0; hh < 8; ++hh) {
            float4 o = CF4(&s_q[(c*8 + hh)*4]);
            o.x += acc[hh].x; o.y += acc[hh].y; o.z += acc[hh].z; o.w += acc[hh].w;
            F4(&facc_out[hh*512 + c*4]) = o;
        }
    }
}

// ============ k4: flash-combine folded into agg GEMM ============
// A_eff[b,kg] = sum_i wgt[b][i] * Facc[i][b][kg], wgt = exp(m_i-M)/D
__global__ __launch_bounds__(256) void k_agg(
    const float* __restrict__ Facc, const float* __restrict__ Fms,
    const float* __restrict__ Wagg, float* __restrict__ P5)
{
    const int nt = blockIdx.x, ks = blockIdx.y;   // nt<8, ks<32
    const int h = ks >> 2;                         // head constant per k-slice
    __shared__ float As[16*64], Ws[16*64], wgt[8*64];
    const int t = threadIdx.x;
    if (t < 64) {
        float mm[8], ss[8], e[8];
        float M = -1e30f;
        #pragma unroll
        for (int i = 0; i < 8; ++i) {
            size_t o = ((size_t)(i*64 + t)*8 + h)*2;
            mm[i] = Fms[o]; ss[i] = Fms[o+1];
            M = fmaxf(M, mm[i]);
        }
        float D = 0.f;
        #pragma unroll
        for (int i = 0; i < 8; ++i) { e[i] = __expf(mm[i] - M); D += e[i]*ss[i]; }
        float invD = 1.f / D;
        #pragma unroll
        for (int i = 0; i < 8; ++i) wgt[i*64 + t] = e[i] * invD;
    }
    __syncthreads();
    const int tx = t & 15, ty = t >> 4;
    const int row = t >> 2, kq = (t & 3) * 4;
    const int wrow = t >> 4, wcol = (t & 15) * 4;
    const int k0 = ks * 128;
    float acc[4][4] = {};
    for (int kk = 0; kk < 128; kk += 16) {
        const int kg = k0 + kk + kq;
        float4 av = {0.f, 0.f, 0.f, 0.f};
        #pragma unroll
        for (int i = 0; i < 8; ++i) {
            float wi = wgt[i*64 + row];
            float4 v = CF4(&Facc[((size_t)(i*64 + row))*4096 + kg]);
            av.x += wi*v.x; av.y += wi*v.y; av.z += wi*v.z; av.w += wi*v.w;
        }
        As[(kq+0)*64+row] = av.x; As[(kq+1)*64+row] = av.y;
        As[(kq+2)*64+row] = av.z; As[(kq+3)*64+row] = av.w;
        F4(&Ws[wrow*64 + wcol]) = CF4(&Wagg[(size_t)(k0 + kk + wrow)*512 + nt*64 + wcol]);
        __syncthreads();
        #pragma unroll
        for (int k = 0; k < 16; ++k) {
            float4 a4 = CF4(&As[k*64 + ty*4]);
            float4 w4 = CF4(&Ws[k*64 + tx*4]);
            float a[4] = {a4.x, a4.y, a4.z, a4.w};
            float w[4] = {w4.x, w4.y, w4.z, w4.w};
            #pragma unroll
            for (int i = 0; i < 4; ++i)
                #pragma unroll
                for (int j = 0; j < 4; ++j)
                    acc[i][j] += a[i] * w[j];
        }
        __syncthreads();
    }
    float* pout = P5 + (size_t)ks*64*512;
    #pragma unroll
    for (int i = 0; i < 4; ++i) {
        float4 o = {acc[i][0], acc[i][1], acc[i][2], acc[i][3]};
        F4(&pout[(size_t)(ty*4 + i)*512 + nt*64 + tx*4]) = o;
    }
}

// ============ k5: P6[z][ks] = (bagg + sum32 P5) @ {Wrk1|Wrv1} ============
__global__ __launch_bounds__(256) void k_rkv1(
    const float* __restrict__ P5, const float* __restrict__ bagg,
    const float* __restrict__ Wrk1, const float* __restrict__ Wrv1,
    float* __restrict__ P6)
{
    const int nt = blockIdx.x, ks = blockIdx.y, z = blockIdx.z;
    gemm_core(P5, bagg, 32, 512, 128, ks*128, z ? Wrv1 : Wrk1, 512, nt*64,
              nullptr, P6 + (size_t)(z*4 + ks)*64*512, 512);
}

// ============ k6: out[z] = (b1 + sum4 P6[z]) @ {Wrk2|Wrv2} + b2 ============
__global__ __launch_bounds__(256) void k_rkv2(
    const float* __restrict__ P6,
    const float* __restrict__ brk1, const float* __restrict__ brv1,
    const float* __restrict__ Wrk2, const float* __restrict__ Wrv2,
    const float* __restrict__ brk2, const float* __restrict__ brv2,
    float* __restrict__ out)
{
    const int nt = blockIdx.x, z = blockIdx.z;
    gemm_core(P6 + (size_t)z*4*64*512, z ? brv1 : brk1, 4, 512, 512, 0,
              z ? Wrv2 : Wrk2, 512, nt*64,
              z ? brv2 : brk2, out + (size_t)z*64*512, 512);
}

// ============ launch ============
extern "C" void kernel_launch(void* const* d_in, const int* in_sizes, int n_in,
                              void* d_out, int out_size, void* d_ws, size_t ws_size,
                              hipStream_t stream) {
    const float* state   = (const float*)d_in[0];
    const float* til     = (const float*)d_in[1];
    const float* keys    = (const float*)d_in[2];
    const float* vals    = (const float*)d_in[3];
    const float* rpe     = (const float*)d_in[4];
    const int*   step    = (const int*)d_in[5];
    const float* W_state = (const float*)d_in[6];
    const float* b_state = (const float*)d_in[7];
    const float* Wcq1 = (const float*)d_in[8];
    const float* bcq1 = (const float*)d_in[9];
    const float* Wcq2 = (const float*)d_in[10];
    const float* bcq2 = (const float*)d_in[11];
    const float* Wq   = (const float*)d_in[12];
    const float* bq   = (const float*)d_in[13];
    const float* Wagg = (const float*)d_in[14];
    const float* bagg = (const float*)d_in[15];
    const float* Wrk1 = (const float*)d_in[16];
    const float* brk1 = (const float*)d_in[17];
    const float* Wrk2 = (const float*)d_in[18];
    const float* brk2 = (const float*)d_in[19];
    const float* Wrv1 = (const float*)d_in[20];
    const float* brv1 = (const float*)d_in[21];
    const float* Wrv2 = (const float*)d_in[22];
    const float* brv2 = (const float*)d_in[23];
    float* out = (float*)d_out;
    float* ws  = (float*)d_ws;

    float* q2buf = ws;             // 64*512        = 32768
    float* qh    = ws + 32768;     // 64*4096       = 262144
    float* Facc  = ws + 294912;    // 8*64*4096     = 2097152
    float* Fms   = ws + 2392064;   // 8*64*8*2      = 8192
    float* P5    = ws + 2400256;   // 32*64*512     = 1048576
    float* P6    = ws + 3448832;   // 2*4*64*512    = 262144

    k_qchain<<<64, 1024, 0, stream>>>(state, til, W_state, b_state,
                                      Wcq1, bcq1, Wcq2, bcq2, q2buf);
    k_qh   <<<64, 256, 0, stream>>>(q2buf, Wq, bq, qh);
    k_fa   <<<dim3(8,64),  256, 0, stream>>>(keys, rpe, qh, vals, step, Facc, Fms);
    k_agg  <<<dim3(8,32),  256, 0, stream>>>(Facc, Fms, Wagg, P5);
    k_rkv1 <<<dim3(8,4,2), 256, 0, stream>>>(P5, bagg, Wrk1, Wrv1, P6);
    k_rkv2 <<<dim3(8,1,2), 256, 0, stream>>>(P6, brk1, brv1, Wrk2, Wrv2,
                                             brk2, brv2, out);
}

// Round 6
// 215.741 us; speedup vs baseline: 3.1737x; 1.0529x over previous
//
#include <hip/hip_runtime.h>
#include <math.h>

#define F4(p)  (*reinterpret_cast<float4*>(p))
#define CF4(p) (*reinterpret_cast<const float4*>(p))
#define CF2(p) (*reinterpret_cast<const float2*>(p))

// ============ k1: per-b query chain, 1024 threads, k-split across waves ============
__global__ __launch_bounds__(1024) void k_qchain(
    const float* __restrict__ state, const float* __restrict__ til,
    const float* __restrict__ W_state, const float* __restrict__ b_state,
    const float* __restrict__ Wcq1, const float* __restrict__ bcq1,
    const float* __restrict__ Wcq2, const float* __restrict__ bcq2,
    float* __restrict__ q2buf)
{
    __shared__ float s_in[512], s_u[512], s_q1[512];
    __shared__ float2 part[1024];
    const int b = blockIdx.x, t = threadIdx.x;
    if (t < 512) s_in[t] = state[b*512 + t];
    __syncthreads();
    {
        const int c = t & 127, kq = t >> 7;
        float2 a = {0.f, 0.f};
        #pragma unroll 8
        for (int k = kq*64; k < kq*64 + 64; ++k) {
            float s = s_in[k];
            float2 w = CF2(&W_state[k*256 + c*2]);
            a.x += s * w.x; a.y += s * w.y;
        }
        part[t] = a;
    }
    __syncthreads();
    if (t < 128) {
        float2 r = CF2(&b_state[t*2]);
        #pragma unroll
        for (int s = 0; s < 8; ++s) { r.x += part[s*128 + t].x; r.y += part[s*128 + t].y; }
        s_u[t*2] = r.x; s_u[t*2+1] = r.y;
    } else if (t < 256) {
        int i = (t - 128) * 2;
        float2 v = CF2(&til[b*256 + i]);
        s_u[256 + i] = v.x; s_u[256 + i + 1] = v.y;
    }
    __syncthreads();
    {
        const int c = t & 255, kq = t >> 8;
        float2 a = {0.f, 0.f};
        #pragma unroll 8
        for (int k = kq*128; k < kq*128 + 128; ++k) {
            float s = s_u[k];
            float2 w = CF2(&Wcq1[k*512 + c*2]);
            a.x += s * w.x; a.y += s * w.y;
        }
        part[t] = a;
    }
    __syncthreads();
    if (t < 256) {
        float2 r = CF2(&bcq1[t*2]);
        #pragma unroll
        for (int s = 0; s < 4; ++s) { r.x += part[s*256 + t].x; r.y += part[s*256 + t].y; }
        s_q1[t*2] = r.x; s_q1[t*2+1] = r.y;
    }
    __syncthreads();
    {
        const int c = t & 255, kq = t >> 8;
        float2 a = {0.f, 0.f};
        #pragma unroll 8
        for (int k = kq*128; k < kq*128 + 128; ++k) {
            float s = s_q1[k];
            float2 w = CF2(&Wcq2[k*512 + c*2]);
            a.x += s * w.x; a.y += s * w.y;
        }
        part[t] = a;
    }
    __syncthreads();
    if (t < 256) {
        float2 r = CF2(&bcq2[t*2]);
        #pragma unroll
        for (int s = 0; s < 4; ++s) { r.x += part[s*256 + t].x; r.y += part[s*256 + t].y; }
        q2buf[b*512 + t*2]   = r.x;
        q2buf[b*512 + t*2+1] = r.y;
    }
}

// ============ shared 64x64-tile GEMM core (256 threads) ============
__device__ __forceinline__ void gemm_core(
    const float* __restrict__ Asrc, const float* __restrict__ inbias,
    int NS, int srcld, int kc, int k0,
    const float* __restrict__ W, int ldw, int n0,
    const float* __restrict__ obias, float* __restrict__ Pout, int ldo)
{
    __shared__ float As[16*64], Ws[16*64];
    const int t = threadIdx.x;
    const int tx = t & 15, ty = t >> 4;
    const int row = t >> 2, kq = (t & 3) * 4;
    const int wrow = t >> 4, wcol = (t & 15) * 4;
    float acc[4][4] = {};
    for (int kk = 0; kk < kc; kk += 16) {
        const int kg = k0 + kk + kq;
        float4 av = {0.f, 0.f, 0.f, 0.f};
        if (inbias) av = CF4(&inbias[kg]);
        for (int s = 0; s < NS; ++s) {
            float4 v = CF4(&Asrc[(size_t)(s*64 + row)*srcld + kg]);
            av.x += v.x; av.y += v.y; av.z += v.z; av.w += v.w;
        }
        As[(kq+0)*64+row] = av.x; As[(kq+1)*64+row] = av.y;
        As[(kq+2)*64+row] = av.z; As[(kq+3)*64+row] = av.w;
        F4(&Ws[wrow*64 + wcol]) = CF4(&W[(size_t)(k0 + kk + wrow)*ldw + n0 + wcol]);
        __syncthreads();
        #pragma unroll
        for (int k = 0; k < 16; ++k) {
            float4 a4 = CF4(&As[k*64 + ty*4]);
            float4 w4 = CF4(&Ws[k*64 + tx*4]);
            float a[4] = {a4.x, a4.y, a4.z, a4.w};
            float w[4] = {w4.x, w4.y, w4.z, w4.w};
            #pragma unroll
            for (int i = 0; i < 4; ++i)
                #pragma unroll
                for (int j = 0; j < 4; ++j)
                    acc[i][j] += a[i] * w[j];
        }
        __syncthreads();
    }
    #pragma unroll
    for (int i = 0; i < 4; ++i) {
        float4 o = {acc[i][0], acc[i][1], acc[i][2], acc[i][3]};
        if (obias) {
            float4 ob = CF4(&obias[n0 + tx*4]);
            o.x += ob.x; o.y += ob.y; o.z += ob.z; o.w += ob.w;
        }
        F4(&Pout[(size_t)(ty*4 + i)*ldo + n0 + tx*4]) = o;
    }
}

// ============ k2: qh = q2 @ Wq + bq ============
__global__ __launch_bounds__(256) void k_qh(
    const float* __restrict__ q2buf, const float* __restrict__ Wq,
    const float* __restrict__ bq, float* __restrict__ qh)
{
    gemm_core(q2buf, nullptr, 1, 512, 512, 0, Wq, 4096, blockIdx.x*64, bq, qh, 4096);
}

// ============ k3: flash attention chunk (64 l per block, 1024 blocks) ============
__global__ __launch_bounds__(256) void k_fa(
    const float* __restrict__ keys, const float* __restrict__ rpe,
    const float* __restrict__ qh, const float* __restrict__ vals,
    const int* __restrict__ step,
    float* __restrict__ Facc, float* __restrict__ Fms)
{
    __shared__ float s_q[4096];
    __shared__ float s_sc[64*8];
    __shared__ float red[256];
    __shared__ float s_m[8];
    const int b = blockIdx.y, lc = blockIdx.x;
    const int sb = step[b];
    const int l0 = lc * 64;
    const int t = threadIdx.x;
    float* facc_out = Facc + ((size_t)(lc*64) + b)*4096;
    if (l0 >= sb) {
        float4 z = {0.f, 0.f, 0.f, 0.f};
        for (int i = t; i < 1024; i += 256) F4(&facc_out[i*4]) = z;
        if (t < 8) {
            size_t o = ((size_t)(lc*64 + b)*8 + t)*2;
            Fms[o] = -1e30f; Fms[o+1] = 0.f;
        }
        return;
    }
    for (int i = t; i < 1024; i += 256)
        F4(&s_q[i*4]) = CF4(&qh[(size_t)b*4096 + i*4]);
    __syncthreads();
    const int lane = t & 63, w = t >> 6;
    float qr[8][8];
    #pragma unroll
    for (int h = 0; h < 8; ++h) {
        float4 x = CF4(&s_q[h*512 + lane*8]);
        float4 y = CF4(&s_q[h*512 + lane*8 + 4]);
        qr[h][0]=x.x; qr[h][1]=x.y; qr[h][2]=x.z; qr[h][3]=x.w;
        qr[h][4]=y.x; qr[h][5]=y.y; qr[h][6]=y.z; qr[h][7]=y.w;
    }
    const int nl = min(64, sb - l0);
    const float inv_sqrtK = 0.04419417382415922f;
    const bool p0 = lane & 1, p1 = lane & 2, p2 = lane & 4;
    // --- scores with software-pipelined key loads ---
    const size_t kstride = (size_t)4*64*512;
    const float* kp = keys + ((size_t)(l0 + w)*64 + b)*512 + lane*8;
    float4 kx, ky;
    if (w < nl) { kx = CF4(kp); ky = CF4(kp + 4); }
    for (int il = w; il < nl; il += 4) {
        float4 nkx, nky;
        if (il + 4 < nl) { nkx = CF4(kp + kstride); nky = CF4(kp + kstride + 4); }
        float kv[8] = {kx.x,kx.y,kx.z,kx.w, ky.x,ky.y,ky.z,ky.w};
        float pr[8] = {};
        #pragma unroll
        for (int h = 0; h < 8; ++h)
            #pragma unroll
            for (int j = 0; j < 8; ++j)
                pr[h] += kv[j] * qr[h][j];
        float w4[4], x2[2], y;
        #pragma unroll
        for (int i = 0; i < 4; ++i) {
            float keep = p0 ? pr[2*i+1] : pr[2*i];
            float send = p0 ? pr[2*i]   : pr[2*i+1];
            w4[i] = keep + __shfl_xor(send, 1);
        }
        #pragma unroll
        for (int i = 0; i < 2; ++i) {
            float keep = p1 ? w4[2*i+1] : w4[2*i];
            float send = p1 ? w4[2*i]   : w4[2*i+1];
            x2[i] = keep + __shfl_xor(send, 2);
        }
        {
            float keep = p2 ? x2[1] : x2[0];
            float send = p2 ? x2[0] : x2[1];
            y = keep + __shfl_xor(send, 4);
        }
        y += __shfl_xor(y, 8);
        y += __shfl_xor(y, 16);
        y += __shfl_xor(y, 32);
        if (lane < 8)
            s_sc[il*8 + lane] = y * rpe[(l0 + il)*64 + b] * inv_sqrtK;
        kx = nkx; ky = nky; kp += kstride;
    }
    __syncthreads();
    // --- local softmax stats ---
    const int h = t & 7, g = t >> 3;
    float m = -1e30f;
    for (int l = g; l < nl; l += 32) m = fmaxf(m, s_sc[l*8 + h]);
    red[g*8 + h] = m;
    __syncthreads();
    #pragma unroll
    for (int s = 16; s; s >>= 1) {
        if (g < s) red[g*8+h] = fmaxf(red[g*8+h], red[(g+s)*8+h]);
        __syncthreads();
    }
    if (t < 8) s_m[t] = red[t];
    __syncthreads();
    float mh = s_m[h], s_acc = 0.f;
    for (int l = g; l < nl; l += 32) {
        float e = __expf(s_sc[l*8 + h] - mh);
        s_sc[l*8 + h] = e;
        s_acc += e;
    }
    red[g*8 + h] = s_acc;
    __syncthreads();
    #pragma unroll
    for (int s = 16; s; s >>= 1) {
        if (g < s) red[g*8+h] += red[(g+s)*8+h];
        __syncthreads();
    }
    if (t < 8) {
        size_t o = ((size_t)(lc*64 + b)*8 + t)*2;
        Fms[o] = s_m[t]; Fms[o+1] = red[t];
    }
    // --- PV with software-pipelined vals loads ---
    const int par = t >> 7, c = t & 127;
    float4 acc[8] = {};
    const size_t vstride = (size_t)2*64*512;
    const float* vp = vals + ((size_t)(l0 + par)*64 + b)*512 + c*4;
    float4 v;
    if (par < nl) v = CF4(vp);
    for (int il = par; il < nl; il += 2) {
        float4 nv;
        if (il + 2 < nl) nv = CF4(vp + vstride);
        float4 pa = CF4(&s_sc[il*8]);
        float4 pb = CF4(&s_sc[il*8 + 4]);
        acc[0].x += pa.x*v.x; acc[0].y += pa.x*v.y; acc[0].z += pa.x*v.z; acc[0].w += pa.x*v.w;
        acc[1].x += pa.y*v.x; acc[1].y += pa.y*v.y; acc[1].z += pa.y*v.z; acc[1].w += pa.y*v.w;
        acc[2].x += pa.z*v.x; acc[2].y += pa.z*v.y; acc[2].z += pa.z*v.z; acc[2].w += pa.z*v.w;
        acc[3].x += pa.w*v.x; acc[3].y += pa.w*v.y; acc[3].z += pa.w*v.z; acc[3].w += pa.w*v.w;
        acc[4].x += pb.x*v.x; acc[4].y += pb.x*v.y; acc[4].z += pb.x*v.z; acc[4].w += pb.x*v.w;
        acc[5].x += pb.y*v.x; acc[5].y += pb.y*v.y; acc[5].z += pb.y*v.z; acc[5].w += pb.y*v.w;
        acc[6].x += pb.z*v.x; acc[6].y += pb.z*v.y; acc[6].z += pb.z*v.z; acc[6].w += pb.z*v.w;
        acc[7].x += pb.w*v.x; acc[7].y += pb.w*v.y; acc[7].z += pb.w*v.z; acc[7].w += pb.w*v.w;
        v = nv; vp += vstride;
    }
    __syncthreads();
    if (par == 1) {
        #pragma unroll
        for (int hh = 0; hh < 8; ++hh)
            F4(&s_q[(c*8 + hh)*4]) = acc[hh];
    }
    __syncthreads();
    if (par == 0) {
        #pragma unroll
        for (int hh = 0; hh < 8; ++hh) {
            float4 o = CF4(&s_q[(c*8 + hh)*4]);
            o.x += acc[hh].x; o.y += acc[hh].y; o.z += acc[hh].z; o.w += acc[hh].w;
            F4(&facc_out[hh*512 + c*4]) = o;
        }
    }
}

// ============ k4: flash combine -> res[64][4096] ============
__global__ __launch_bounds__(256) void k_comb(
    const float* __restrict__ Facc, const float* __restrict__ Fms,
    float* __restrict__ res)
{
    __shared__ float wgt[16*8];
    const int b = blockIdx.x, t = threadIdx.x;
    if (t < 8) {
        float mm[16], ss[16], e[16];
        float M = -1e30f;
        #pragma unroll
        for (int i = 0; i < 16; ++i) {
            size_t o = ((size_t)(i*64 + b)*8 + t)*2;
            mm[i] = Fms[o]; ss[i] = Fms[o+1];
            M = fmaxf(M, mm[i]);
        }
        float D = 0.f;
        #pragma unroll
        for (int i = 0; i < 16; ++i) { e[i] = __expf(mm[i] - M); D += e[i]*ss[i]; }
        float invD = 1.f / D;
        #pragma unroll
        for (int i = 0; i < 16; ++i) wgt[i*8 + t] = e[i] * invD;
    }
    __syncthreads();
    #pragma unroll
    for (int j = 0; j < 4; ++j) {
        int f = t + j*256;          // f4 index within [0,1024)
        int h = f >> 7;
        float4 a = {0.f, 0.f, 0.f, 0.f};
        #pragma unroll
        for (int i = 0; i < 16; ++i) {
            float wi = wgt[i*8 + h];
            float4 v = CF4(&Facc[((size_t)(i*64) + b)*4096 + f*4]);
            a.x += wi*v.x; a.y += wi*v.y; a.z += wi*v.z; a.w += wi*v.w;
        }
        F4(&res[(size_t)b*4096 + f*4]) = a;
    }
}

// ============ k5: P5[ks] = res @ Wagg (split-K) ============
__global__ __launch_bounds__(256) void k_agg(
    const float* __restrict__ res, const float* __restrict__ Wagg,
    float* __restrict__ P5)
{
    const int nt = blockIdx.x, ks = blockIdx.y;
    gemm_core(res, nullptr, 1, 4096, 128, ks*128, Wagg, 512, nt*64,
              nullptr, P5 + (size_t)ks*64*512, 512);
}

// ============ k6: P6[z][ks] = (bagg + sum32 P5) @ {Wrk1|Wrv1} ============
__global__ __launch_bounds__(256) void k_rkv1(
    const float* __restrict__ P5, const float* __restrict__ bagg,
    const float* __restrict__ Wrk1, const float* __restrict__ Wrv1,
    float* __restrict__ P6)
{
    const int nt = blockIdx.x, ks = blockIdx.y, z = blockIdx.z;
    gemm_core(P5, bagg, 32, 512, 128, ks*128, z ? Wrv1 : Wrk1, 512, nt*64,
              nullptr, P6 + (size_t)(z*4 + ks)*64*512, 512);
}

// ============ k7: out[z] = (b1 + sum4 P6[z]) @ {Wrk2|Wrv2} + b2 ============
__global__ __launch_bounds__(256) void k_rkv2(
    const float* __restrict__ P6,
    const float* __restrict__ brk1, const float* __restrict__ brv1,
    const float* __restrict__ Wrk2, const float* __restrict__ Wrv2,
    const float* __restrict__ brk2, const float* __restrict__ brv2,
    float* __restrict__ out)
{
    const int nt = blockIdx.x, z = blockIdx.z;
    gemm_core(P6 + (size_t)z*4*64*512, z ? brv1 : brk1, 4, 512, 512, 0,
              z ? Wrv2 : Wrk2, 512, nt*64,
              z ? brv2 : brk2, out + (size_t)z*64*512, 512);
}

// ============ launch ============
extern "C" void kernel_launch(void* const* d_in, const int* in_sizes, int n_in,
                              void* d_out, int out_size, void* d_ws, size_t ws_size,
                              hipStream_t stream) {
    const float* state   = (const float*)d_in[0];
    const float* til     = (const float*)d_in[1];
    const float* keys    = (const float*)d_in[2];
    const float* vals    = (const float*)d_in[3];
    const float* rpe     = (const float*)d_in[4];
    const int*   step    = (const int*)d_in[5];
    const float* W_state = (const float*)d_in[6];
    const float* b_state = (const float*)d_in[7];
    const float* Wcq1 = (const float*)d_in[8];
    const float* bcq1 = (const float*)d_in[9];
    const float* Wcq2 = (const float*)d_in[10];
    const float* bcq2 = (const float*)d_in[11];
    const float* Wq   = (const float*)d_in[12];
    const float* bq   = (const float*)d_in[13];
    const float* Wagg = (const float*)d_in[14];
    const float* bagg = (const float*)d_in[15];
    const float* Wrk1 = (const float*)d_in[16];
    const float* brk1 = (const float*)d_in[17];
    const float* Wrk2 = (const float*)d_in[18];
    const float* brk2 = (const float*)d_in[19];
    const float* Wrv1 = (const float*)d_in[20];
    const float* brv1 = (const float*)d_in[21];
    const float* Wrv2 = (const float*)d_in[22];
    const float* brv2 = (const float*)d_in[23];
    float* out = (float*)d_out;
    float* ws  = (float*)d_ws;

    float* q2buf = ws;             // 64*512         = 32768
    float* qh    = ws + 32768;     // 64*4096        = 262144
    float* Facc  = ws + 294912;    // 16*64*4096     = 4194304
    float* Fms   = ws + 4489216;   // 16*64*8*2      = 16384
    float* res   = ws + 4505600;   // 64*4096        = 262144
    float* P5    = ws + 4767744;   // 32*64*512      = 1048576
    float* P6    = ws + 5816320;   // 2*4*64*512     = 262144

    k_qchain<<<64, 1024, 0, stream>>>(state, til, W_state, b_state,
                                      Wcq1, bcq1, Wcq2, bcq2, q2buf);
    k_qh   <<<64, 256, 0, stream>>>(q2buf, Wq, bq, qh);
    k_fa   <<<dim3(16,64), 256, 0, stream>>>(keys, rpe, qh, vals, step, Facc, Fms);
    k_comb <<<64, 256, 0, stream>>>(Facc, Fms, res);
    k_agg  <<<dim3(8,32),  256, 0, stream>>>(res, Wagg, P5);
    k_rkv1 <<<dim3(8,4,2), 256, 0, stream>>>(P5, bagg, Wrk1, Wrv1, P6);
    k_rkv2 <<<dim3(8,1,2), 256, 0, stream>>>(P6, brk1, brv1, Wrk2, Wrv2,
                                             brk2, brv2, out);
}

// Round 7
// 166.305 us; speedup vs baseline: 4.1172x; 1.2973x over previous
//
#include <hip/hip_runtime.h>
#include <math.h>

#define F4(p)  (*reinterpret_cast<float4*>(p))
#define CF4(p) (*reinterpret_cast<const float4*>(p))

// ============ shared 64x64-tile GEMM core (256 threads) ============
// A_eff[m,kg] = til && kg>=256 ? til[m*256+kg-256]
//             : (inbias?inbias[kg]:0) + sum_{s<NS} Asrc[(s*64+m)*srcld+kg]
// Pout[m, n0+n] = acc + (obias?obias[n0+n]:0)
__device__ __forceinline__ void gemm_core(
    const float* __restrict__ Asrc, const float* __restrict__ inbias,
    const float* __restrict__ til,
    int NS, int srcld, int kc, int k0,
    const float* __restrict__ W, int ldw, int n0,
    const float* __restrict__ obias, float* __restrict__ Pout, int ldo)
{
    __shared__ float As[16*64], Ws[16*64];
    const int t = threadIdx.x;
    const int tx = t & 15, ty = t >> 4;
    const int row = t >> 2, kq = (t & 3) * 4;
    const int wrow = t >> 4, wcol = (t & 15) * 4;
    float acc[4][4] = {};
    for (int kk = 0; kk < kc; kk += 16) {
        const int kg = k0 + kk + kq;
        float4 av;
        if (til && kg >= 256) {
            av = CF4(&til[row*256 + (kg - 256)]);
        } else {
            av = {0.f, 0.f, 0.f, 0.f};
            if (inbias) av = CF4(&inbias[kg]);
            for (int s = 0; s < NS; ++s) {
                float4 v = CF4(&Asrc[(size_t)(s*64 + row)*srcld + kg]);
                av.x += v.x; av.y += v.y; av.z += v.z; av.w += v.w;
            }
        }
        As[(kq+0)*64+row] = av.x; As[(kq+1)*64+row] = av.y;
        As[(kq+2)*64+row] = av.z; As[(kq+3)*64+row] = av.w;
        F4(&Ws[wrow*64 + wcol]) = CF4(&W[(size_t)(k0 + kk + wrow)*ldw + n0 + wcol]);
        __syncthreads();
        #pragma unroll
        for (int k = 0; k < 16; ++k) {
            float4 a4 = CF4(&As[k*64 + ty*4]);
            float4 w4 = CF4(&Ws[k*64 + tx*4]);
            float a[4] = {a4.x, a4.y, a4.z, a4.w};
            float w[4] = {w4.x, w4.y, w4.z, w4.w};
            #pragma unroll
            for (int i = 0; i < 4; ++i)
                #pragma unroll
                for (int j = 0; j < 4; ++j)
                    acc[i][j] += a[i] * w[j];
        }
        __syncthreads();
    }
    #pragma unroll
    for (int i = 0; i < 4; ++i) {
        float4 o = {acc[i][0], acc[i][1], acc[i][2], acc[i][3]};
        if (obias) {
            float4 ob = CF4(&obias[n0 + tx*4]);
            o.x += ob.x; o.y += ob.y; o.z += ob.z; o.w += ob.w;
        }
        F4(&Pout[(size_t)(ty*4 + i)*ldo + n0 + tx*4]) = o;
    }
}

// ============ q-chain as split-K GEMMs ============
__global__ __launch_bounds__(256) void k_q1(
    const float* __restrict__ state, const float* __restrict__ W_state,
    float* __restrict__ P1)
{
    const int nt = blockIdx.x, ks = blockIdx.y;     // 4 x 8
    gemm_core(state, nullptr, nullptr, 1, 512, 64, ks*64,
              W_state, 256, nt*64, nullptr, P1 + (size_t)ks*64*256, 256);
}

__global__ __launch_bounds__(256) void k_q2(
    const float* __restrict__ P1, const float* __restrict__ b_state,
    const float* __restrict__ til, const float* __restrict__ Wcq1,
    float* __restrict__ P2)
{
    const int nt = blockIdx.x, ks = blockIdx.y;     // 8 x 8
    gemm_core(P1, b_state, til, 8, 256, 64, ks*64,
              Wcq1, 512, nt*64, nullptr, P2 + (size_t)ks*64*512, 512);
}

__global__ __launch_bounds__(256) void k_q3(
    const float* __restrict__ P2, const float* __restrict__ bcq1,
    const float* __restrict__ Wcq2, float* __restrict__ P3)
{
    const int nt = blockIdx.x, ks = blockIdx.y;     // 8 x 8
    gemm_core(P2, bcq1, nullptr, 8, 512, 64, ks*64,
              Wcq2, 512, nt*64, nullptr, P3 + (size_t)ks*64*512, 512);
}

__global__ __launch_bounds__(256) void k_qh(
    const float* __restrict__ P3, const float* __restrict__ bcq2,
    const float* __restrict__ Wq, float* __restrict__ P4)
{
    const int nt = blockIdx.x, ks = blockIdx.y;     // 64 x 4
    gemm_core(P3, bcq2, nullptr, 8, 512, 128, ks*128,
              Wq, 4096, nt*64, nullptr, P4 + (size_t)ks*64*4096, 4096);
}

// ============ k_fa: flash attention chunk (64 l per block, 1024 blocks) ============
__global__ __launch_bounds__(256) void k_fa(
    const float* __restrict__ keys, const float* __restrict__ rpe,
    const float* __restrict__ P4, const float* __restrict__ bq,
    const float* __restrict__ vals, const int* __restrict__ step,
    float* __restrict__ Facc, float* __restrict__ Fms)
{
    __shared__ float s_q[4096];
    __shared__ float s_sc[64*8];
    __shared__ float red[256];
    __shared__ float s_m[8];
    const int b = blockIdx.y, lc = blockIdx.x;
    const int sb = step[b];
    const int l0 = lc * 64;
    const int t = threadIdx.x;
    float* facc_out = Facc + ((size_t)(lc*64) + b)*4096;
    if (l0 >= sb) {
        float4 z = {0.f, 0.f, 0.f, 0.f};
        for (int i = t; i < 1024; i += 256) F4(&facc_out[i*4]) = z;
        if (t < 8) {
            size_t o = ((size_t)(lc*64 + b)*8 + t)*2;
            Fms[o] = -1e30f; Fms[o+1] = 0.f;
        }
        return;
    }
    // stage q_eff[b] = bq + sum of 4 P4 partials
    for (int i = t; i < 1024; i += 256) {
        float4 v = CF4(&bq[i*4]);
        #pragma unroll
        for (int s = 0; s < 4; ++s) {
            float4 u = CF4(&P4[(size_t)(s*64 + b)*4096 + i*4]);
            v.x += u.x; v.y += u.y; v.z += u.z; v.w += u.w;
        }
        F4(&s_q[i*4]) = v;
    }
    __syncthreads();
    const int lane = t & 63, w = t >> 6;
    float qr[8][8];
    #pragma unroll
    for (int h = 0; h < 8; ++h) {
        float4 x = CF4(&s_q[h*512 + lane*8]);
        float4 y = CF4(&s_q[h*512 + lane*8 + 4]);
        qr[h][0]=x.x; qr[h][1]=x.y; qr[h][2]=x.z; qr[h][3]=x.w;
        qr[h][4]=y.x; qr[h][5]=y.y; qr[h][6]=y.z; qr[h][7]=y.w;
    }
    const int nl = min(64, sb - l0);
    const float inv_sqrtK = 0.04419417382415922f;
    const bool p0 = lane & 1, p1 = lane & 2, p2 = lane & 4;
    // --- scores with software-pipelined key loads ---
    const size_t kstride = (size_t)4*64*512;
    const float* kp = keys + ((size_t)(l0 + w)*64 + b)*512 + lane*8;
    float4 kx, ky;
    if (w < nl) { kx = CF4(kp); ky = CF4(kp + 4); }
    for (int il = w; il < nl; il += 4) {
        float4 nkx, nky;
        if (il + 4 < nl) { nkx = CF4(kp + kstride); nky = CF4(kp + kstride + 4); }
        float kv[8] = {kx.x,kx.y,kx.z,kx.w, ky.x,ky.y,ky.z,ky.w};
        float pr[8] = {};
        #pragma unroll
        for (int h = 0; h < 8; ++h)
            #pragma unroll
            for (int j = 0; j < 8; ++j)
                pr[h] += kv[j] * qr[h][j];
        float w4[4], x2[2], y;
        #pragma unroll
        for (int i = 0; i < 4; ++i) {
            float keep = p0 ? pr[2*i+1] : pr[2*i];
            float send = p0 ? pr[2*i]   : pr[2*i+1];
            w4[i] = keep + __shfl_xor(send, 1);
        }
        #pragma unroll
        for (int i = 0; i < 2; ++i) {
            float keep = p1 ? w4[2*i+1] : w4[2*i];
            float send = p1 ? w4[2*i]   : w4[2*i+1];
            x2[i] = keep + __shfl_xor(send, 2);
        }
        {
            float keep = p2 ? x2[1] : x2[0];
            float send = p2 ? x2[0] : x2[1];
            y = keep + __shfl_xor(send, 4);
        }
        y += __shfl_xor(y, 8);
        y += __shfl_xor(y, 16);
        y += __shfl_xor(y, 32);
        if (lane < 8)
            s_sc[il*8 + lane] = y * rpe[(l0 + il)*64 + b] * inv_sqrtK;
        kx = nkx; ky = nky; kp += kstride;
    }
    __syncthreads();
    // --- local softmax stats ---
    const int h = t & 7, g = t >> 3;
    float m = -1e30f;
    for (int l = g; l < nl; l += 32) m = fmaxf(m, s_sc[l*8 + h]);
    red[g*8 + h] = m;
    __syncthreads();
    #pragma unroll
    for (int s = 16; s; s >>= 1) {
        if (g < s) red[g*8+h] = fmaxf(red[g*8+h], red[(g+s)*8+h]);
        __syncthreads();
    }
    if (t < 8) s_m[t] = red[t];
    __syncthreads();
    float mh = s_m[h], s_acc = 0.f;
    for (int l = g; l < nl; l += 32) {
        float e = __expf(s_sc[l*8 + h] - mh);
        s_sc[l*8 + h] = e;
        s_acc += e;
    }
    red[g*8 + h] = s_acc;
    __syncthreads();
    #pragma unroll
    for (int s = 16; s; s >>= 1) {
        if (g < s) red[g*8+h] += red[(g+s)*8+h];
        __syncthreads();
    }
    if (t < 8) {
        size_t o = ((size_t)(lc*64 + b)*8 + t)*2;
        Fms[o] = s_m[t]; Fms[o+1] = red[t];
    }
    // --- PV with software-pipelined vals loads ---
    const int par = t >> 7, c = t & 127;
    float4 acc[8] = {};
    const size_t vstride = (size_t)2*64*512;
    const float* vp = vals + ((size_t)(l0 + par)*64 + b)*512 + c*4;
    float4 v;
    if (par < nl) v = CF4(vp);
    for (int il = par; il < nl; il += 2) {
        float4 nv;
        if (il + 2 < nl) nv = CF4(vp + vstride);
        float4 pa = CF4(&s_sc[il*8]);
        float4 pb = CF4(&s_sc[il*8 + 4]);
        acc[0].x += pa.x*v.x; acc[0].y += pa.x*v.y; acc[0].z += pa.x*v.z; acc[0].w += pa.x*v.w;
        acc[1].x += pa.y*v.x; acc[1].y += pa.y*v.y; acc[1].z += pa.y*v.z; acc[1].w += pa.y*v.w;
        acc[2].x += pa.z*v.x; acc[2].y += pa.z*v.y; acc[2].z += pa.z*v.z; acc[2].w += pa.z*v.w;
        acc[3].x += pa.w*v.x; acc[3].y += pa.w*v.y; acc[3].z += pa.w*v.z; acc[3].w += pa.w*v.w;
        acc[4].x += pb.x*v.x; acc[4].y += pb.x*v.y; acc[4].z += pb.x*v.z; acc[4].w += pb.x*v.w;
        acc[5].x += pb.y*v.x; acc[5].y += pb.y*v.y; acc[5].z += pb.y*v.z; acc[5].w += pb.y*v.w;
        acc[6].x += pb.z*v.x; acc[6].y += pb.z*v.y; acc[6].z += pb.z*v.z; acc[6].w += pb.z*v.w;
        acc[7].x += pb.w*v.x; acc[7].y += pb.w*v.y; acc[7].z += pb.w*v.z; acc[7].w += pb.w*v.w;
        v = nv; vp += vstride;
    }
    __syncthreads();
    if (par == 1) {
        #pragma unroll
        for (int hh = 0; hh < 8; ++hh)
            F4(&s_q[(c*8 + hh)*4]) = acc[hh];
    }
    __syncthreads();
    if (par == 0) {
        #pragma unroll
        for (int hh = 0; hh < 8; ++hh) {
            float4 o = CF4(&s_q[(c*8 + hh)*4]);
            o.x += acc[hh].x; o.y += acc[hh].y; o.z += acc[hh].z; o.w += acc[hh].w;
            F4(&facc_out[hh*512 + c*4]) = o;
        }
    }
}

// ============ k_comb: flash combine -> res[64][4096] ============
__global__ __launch_bounds__(256) void k_comb(
    const float* __restrict__ Facc, const float* __restrict__ Fms,
    float* __restrict__ res)
{
    __shared__ float wgt[16*8];
    const int b = blockIdx.x, t = threadIdx.x;
    if (t < 8) {
        float mm[16], ss[16], e[16];
        float M = -1e30f;
        #pragma unroll
        for (int i = 0; i < 16; ++i) {
            size_t o = ((size_t)(i*64 + b)*8 + t)*2;
            mm[i] = Fms[o]; ss[i] = Fms[o+1];
            M = fmaxf(M, mm[i]);
        }
        float D = 0.f;
        #pragma unroll
        for (int i = 0; i < 16; ++i) { e[i] = __expf(mm[i] - M); D += e[i]*ss[i]; }
        float invD = 1.f / D;
        #pragma unroll
        for (int i = 0; i < 16; ++i) wgt[i*8 + t] = e[i] * invD;
    }
    __syncthreads();
    #pragma unroll
    for (int j = 0; j < 4; ++j) {
        int f = t + j*256;
        int h = f >> 7;
        float4 a = {0.f, 0.f, 0.f, 0.f};
        #pragma unroll
        for (int i = 0; i < 16; ++i) {
            float wi = wgt[i*8 + h];
            float4 v = CF4(&Facc[((size_t)(i*64) + b)*4096 + f*4]);
            a.x += wi*v.x; a.y += wi*v.y; a.z += wi*v.z; a.w += wi*v.w;
        }
        F4(&res[(size_t)b*4096 + f*4]) = a;
    }
}

// ============ tail GEMMs ============
__global__ __launch_bounds__(256) void k_agg(
    const float* __restrict__ res, const float* __restrict__ Wagg,
    float* __restrict__ P5)
{
    const int nt = blockIdx.x, ks = blockIdx.y;     // 8 x 32
    gemm_core(res, nullptr, nullptr, 1, 4096, 128, ks*128,
              Wagg, 512, nt*64, nullptr, P5 + (size_t)ks*64*512, 512);
}

__global__ __launch_bounds__(256) void k_rkv1(
    const float* __restrict__ P5, const float* __restrict__ bagg,
    const float* __restrict__ Wrk1, const float* __restrict__ Wrv1,
    float* __restrict__ P6)
{
    const int nt = blockIdx.x, ks = blockIdx.y, z = blockIdx.z;  // 8 x 4 x 2
    gemm_core(P5, bagg, nullptr, 32, 512, 128, ks*128,
              z ? Wrv1 : Wrk1, 512, nt*64,
              nullptr, P6 + (size_t)(z*4 + ks)*64*512, 512);
}

__global__ __launch_bounds__(256) void k_rkv2(
    const float* __restrict__ P6,
    const float* __restrict__ brk1, const float* __restrict__ brv1,
    const float* __restrict__ Wrk2, const float* __restrict__ Wrv2,
    const float* __restrict__ brk2, const float* __restrict__ brv2,
    float* __restrict__ out)
{
    const int nt = blockIdx.x, z = blockIdx.z;      // 8 x 1 x 2
    gemm_core(P6 + (size_t)z*4*64*512, z ? brv1 : brk1, nullptr, 4, 512, 512, 0,
              z ? Wrv2 : Wrk2, 512, nt*64,
              z ? brv2 : brk2, out + (size_t)z*64*512, 512);
}

// ============ launch ============
extern "C" void kernel_launch(void* const* d_in, const int* in_sizes, int n_in,
                              void* d_out, int out_size, void* d_ws, size_t ws_size,
                              hipStream_t stream) {
    const float* state   = (const float*)d_in[0];
    const float* til     = (const float*)d_in[1];
    const float* keys    = (const float*)d_in[2];
    const float* vals    = (const float*)d_in[3];
    const float* rpe     = (const float*)d_in[4];
    const int*   step    = (const int*)d_in[5];
    const float* W_state = (const float*)d_in[6];
    const float* b_state = (const float*)d_in[7];
    const float* Wcq1 = (const float*)d_in[8];
    const float* bcq1 = (const float*)d_in[9];
    const float* Wcq2 = (const float*)d_in[10];
    const float* bcq2 = (const float*)d_in[11];
    const float* Wq   = (const float*)d_in[12];
    const float* bq   = (const float*)d_in[13];
    const float* Wagg = (const float*)d_in[14];
    const float* bagg = (const float*)d_in[15];
    const float* Wrk1 = (const float*)d_in[16];
    const float* brk1 = (const float*)d_in[17];
    const float* Wrk2 = (const float*)d_in[18];
    const float* brk2 = (const float*)d_in[19];
    const float* Wrv1 = (const float*)d_in[20];
    const float* brv1 = (const float*)d_in[21];
    const float* Wrv2 = (const float*)d_in[22];
    const float* brv2 = (const float*)d_in[23];
    float* out = (float*)d_out;
    float* ws  = (float*)d_ws;

    // liveness-based layout (23.7 MB)
    float* P1   = ws;              // [8][64][256]  131072   dead after k_q2
    float* P2   = ws + 131072;     // [8][64][512]  262144   dead after k_q3
    float* P3   = ws + 393216;     // [8][64][512]  262144   dead after k_qh
    float* P4   = ws + 655360;     // [4][64][4096] 1048576  dead after k_fa
    float* P5   = ws;              // [32][64][512] 1048576  (reuses P1..P4 region)
    float* P6   = ws + 1048576;    // [2][4][64][512] 262144
    float* res  = ws + 1310720;    // [64][4096]    262144
    float* Facc = ws + 1703936;    // [16][64][4096] 4194304
    float* Fms  = ws + 5898240;    // 16*64*8*2     16384

    k_q1  <<<dim3(4,8),   256, 0, stream>>>(state, W_state, P1);
    k_q2  <<<dim3(8,8),   256, 0, stream>>>(P1, b_state, til, Wcq1, P2);
    k_q3  <<<dim3(8,8),   256, 0, stream>>>(P2, bcq1, Wcq2, P3);
    k_qh  <<<dim3(64,4),  256, 0, stream>>>(P3, bcq2, Wq, P4);
    k_fa  <<<dim3(16,64), 256, 0, stream>>>(keys, rpe, P4, bq, vals, step, Facc, Fms);
    k_comb<<<64, 256, 0, stream>>>(Facc, Fms, res);
    k_agg <<<dim3(8,32),  256, 0, stream>>>(res, Wagg, P5);
    k_rkv1<<<dim3(8,4,2), 256, 0, stream>>>(P5, bagg, Wrk1, Wrv1, P6);
    k_rkv2<<<dim3(8,1,2), 256, 0, stream>>>(P6, brk1, brv1, Wrk2, Wrv2,
                                            brk2, brv2, out);
}

// Round 8
// 156.240 us; speedup vs baseline: 4.3824x; 1.0644x over previous
//
#include <hip/hip_runtime.h>
#include <math.h>

#define F4(p)  (*reinterpret_cast<float4*>(p))
#define CF4(p) (*reinterpret_cast<const float4*>(p))

// ============ shared 64x64-tile GEMM core (256 threads) ============
__device__ __forceinline__ void gemm_core(
    const float* __restrict__ Asrc, const float* __restrict__ inbias,
    const float* __restrict__ til,
    int NS, int srcld, int kc, int k0,
    const float* __restrict__ W, int ldw, int n0,
    const float* __restrict__ obias, float* __restrict__ Pout, int ldo)
{
    __shared__ float As[16*64], Ws[16*64];
    const int t = threadIdx.x;
    const int tx = t & 15, ty = t >> 4;
    const int row = t >> 2, kq = (t & 3) * 4;
    const int wrow = t >> 4, wcol = (t & 15) * 4;
    float acc[4][4] = {};
    for (int kk = 0; kk < kc; kk += 16) {
        const int kg = k0 + kk + kq;
        float4 av;
        if (til && kg >= 256) {
            av = CF4(&til[row*256 + (kg - 256)]);
        } else {
            av = {0.f, 0.f, 0.f, 0.f};
            if (inbias) av = CF4(&inbias[kg]);
            for (int s = 0; s < NS; ++s) {
                float4 v = CF4(&Asrc[(size_t)(s*64 + row)*srcld + kg]);
                av.x += v.x; av.y += v.y; av.z += v.z; av.w += v.w;
            }
        }
        As[(kq+0)*64+row] = av.x; As[(kq+1)*64+row] = av.y;
        As[(kq+2)*64+row] = av.z; As[(kq+3)*64+row] = av.w;
        F4(&Ws[wrow*64 + wcol]) = CF4(&W[(size_t)(k0 + kk + wrow)*ldw + n0 + wcol]);
        __syncthreads();
        #pragma unroll
        for (int k = 0; k < 16; ++k) {
            float4 a4 = CF4(&As[k*64 + ty*4]);
            float4 w4 = CF4(&Ws[k*64 + tx*4]);
            float a[4] = {a4.x, a4.y, a4.z, a4.w};
            float w[4] = {w4.x, w4.y, w4.z, w4.w};
            #pragma unroll
            for (int i = 0; i < 4; ++i)
                #pragma unroll
                for (int j = 0; j < 4; ++j)
                    acc[i][j] += a[i] * w[j];
        }
        __syncthreads();
    }
    #pragma unroll
    for (int i = 0; i < 4; ++i) {
        float4 o = {acc[i][0], acc[i][1], acc[i][2], acc[i][3]};
        if (obias) {
            float4 ob = CF4(&obias[n0 + tx*4]);
            o.x += ob.x; o.y += ob.y; o.z += ob.z; o.w += ob.w;
        }
        F4(&Pout[(size_t)(ty*4 + i)*ldo + n0 + tx*4]) = o;
    }
}

// ============ q-chain as split-K GEMMs ============
__global__ __launch_bounds__(256) void k_q1(
    const float* __restrict__ state, const float* __restrict__ W_state,
    float* __restrict__ P1)
{
    const int nt = blockIdx.x, ks = blockIdx.y;     // 4 x 8
    gemm_core(state, nullptr, nullptr, 1, 512, 64, ks*64,
              W_state, 256, nt*64, nullptr, P1 + (size_t)ks*64*256, 256);
}

__global__ __launch_bounds__(256) void k_q2(
    const float* __restrict__ P1, const float* __restrict__ b_state,
    const float* __restrict__ til, const float* __restrict__ Wcq1,
    float* __restrict__ P2)
{
    const int nt = blockIdx.x, ks = blockIdx.y;     // 8 x 8
    gemm_core(P1, b_state, til, 8, 256, 64, ks*64,
              Wcq1, 512, nt*64, nullptr, P2 + (size_t)ks*64*512, 512);
}

__global__ __launch_bounds__(256) void k_q3(
    const float* __restrict__ P2, const float* __restrict__ bcq1,
    const float* __restrict__ Wcq2, float* __restrict__ P3)
{
    const int nt = blockIdx.x, ks = blockIdx.y;     // 8 x 8
    gemm_core(P2, bcq1, nullptr, 8, 512, 64, ks*64,
              Wcq2, 512, nt*64, nullptr, P3 + (size_t)ks*64*512, 512);
}

__global__ __launch_bounds__(256) void k_qh(
    const float* __restrict__ P3, const float* __restrict__ bcq2,
    const float* __restrict__ Wq, float* __restrict__ P4)
{
    const int nt = blockIdx.x, ks = blockIdx.y;     // 64 x 4
    gemm_core(P3, bcq2, nullptr, 8, 512, 128, ks*128,
              Wq, 4096, nt*64, nullptr, P4 + (size_t)ks*64*4096, 4096);
}

// ============ k_qsum: qh[b] = bq + sum4 P4 ============
__global__ __launch_bounds__(256) void k_qsum(
    const float* __restrict__ P4, const float* __restrict__ bq,
    float* __restrict__ qh)
{
    const int b = blockIdx.x, t = threadIdx.x;
    #pragma unroll
    for (int j = 0; j < 4; ++j) {
        int f = t + j*256;
        float4 v = CF4(&bq[f*4]);
        #pragma unroll
        for (int s = 0; s < 4; ++s) {
            float4 u = CF4(&P4[(size_t)(s*64 + b)*4096 + f*4]);
            v.x += u.x; v.y += u.y; v.z += u.z; v.w += u.w;
        }
        F4(&qh[(size_t)b*4096 + f*4]) = v;
    }
}

// ============ k_fa: flash attention, balanced dynamic chunks ============
__global__ __launch_bounds__(256) void k_fa(
    const float* __restrict__ keys, const float* __restrict__ rpe,
    const float* __restrict__ qh, const float* __restrict__ vals,
    const int* __restrict__ step,
    float* __restrict__ Facc, float* __restrict__ Fms)
{
    __shared__ float s_q[4096];
    __shared__ float s_sc[64*8];
    __shared__ float red[256];
    __shared__ float s_m[8];
    const int b = blockIdx.y, lc = blockIdx.x;
    const int sb = step[b];
    const int l0 = (lc * sb) >> 4;
    const int l1 = ((lc + 1) * sb) >> 4;
    const int nl = l1 - l0;
    const int t = threadIdx.x;
    float* facc_out = Facc + ((size_t)(lc*64) + b)*4096;
    if (nl <= 0) {
        float4 z = {0.f, 0.f, 0.f, 0.f};
        for (int i = t; i < 1024; i += 256) F4(&facc_out[i*4]) = z;
        if (t < 8) {
            size_t o = ((size_t)(lc*64 + b)*8 + t)*2;
            Fms[o] = -1e30f; Fms[o+1] = 0.f;
        }
        return;
    }
    for (int i = t; i < 1024; i += 256)
        F4(&s_q[i*4]) = CF4(&qh[(size_t)b*4096 + i*4]);
    __syncthreads();
    const int lane = t & 63, w = t >> 6;
    float qr[8][8];
    #pragma unroll
    for (int h = 0; h < 8; ++h) {
        float4 x = CF4(&s_q[h*512 + lane*8]);
        float4 y = CF4(&s_q[h*512 + lane*8 + 4]);
        qr[h][0]=x.x; qr[h][1]=x.y; qr[h][2]=x.z; qr[h][3]=x.w;
        qr[h][4]=y.x; qr[h][5]=y.y; qr[h][6]=y.z; qr[h][7]=y.w;
    }
    const float inv_sqrtK = 0.04419417382415922f;
    const bool p0 = lane & 1, p1 = lane & 2, p2 = lane & 4;
    // --- scores, depth-2 prefetch ring ---
    const size_t kstride = (size_t)4*64*512;
    const float* kp = keys + ((size_t)(l0 + w)*64 + b)*512 + lane*8;
    float4 k0x, k0y, k1x, k1y;
    if (w < nl)     { k0x = CF4(kp);           k0y = CF4(kp + 4); }
    if (w + 4 < nl) { k1x = CF4(kp + kstride); k1y = CF4(kp + kstride + 4); }
    for (int il = w; il < nl; il += 4) {
        float kv[8] = {k0x.x,k0x.y,k0x.z,k0x.w, k0y.x,k0y.y,k0y.z,k0y.w};
        k0x = k1x; k0y = k1y;
        if (il + 8 < nl) { k1x = CF4(kp + 2*kstride); k1y = CF4(kp + 2*kstride + 4); }
        kp += kstride;
        float pr[8] = {};
        #pragma unroll
        for (int h = 0; h < 8; ++h)
            #pragma unroll
            for (int j = 0; j < 8; ++j)
                pr[h] += kv[j] * qr[h][j];
        float w4[4], x2[2], y;
        #pragma unroll
        for (int i = 0; i < 4; ++i) {
            float keep = p0 ? pr[2*i+1] : pr[2*i];
            float send = p0 ? pr[2*i]   : pr[2*i+1];
            w4[i] = keep + __shfl_xor(send, 1);
        }
        #pragma unroll
        for (int i = 0; i < 2; ++i) {
            float keep = p1 ? w4[2*i+1] : w4[2*i];
            float send = p1 ? w4[2*i]   : w4[2*i+1];
            x2[i] = keep + __shfl_xor(send, 2);
        }
        {
            float keep = p2 ? x2[1] : x2[0];
            float send = p2 ? x2[0] : x2[1];
            y = keep + __shfl_xor(send, 4);
        }
        y += __shfl_xor(y, 8);
        y += __shfl_xor(y, 16);
        y += __shfl_xor(y, 32);
        if (lane < 8)
            s_sc[il*8 + lane] = y * rpe[(l0 + il)*64 + b] * inv_sqrtK;
    }
    __syncthreads();
    // --- local softmax stats ---
    const int h = t & 7, g = t >> 3;
    float m = -1e30f;
    for (int l = g; l < nl; l += 32) m = fmaxf(m, s_sc[l*8 + h]);
    red[g*8 + h] = m;
    __syncthreads();
    #pragma unroll
    for (int s = 16; s; s >>= 1) {
        if (g < s) red[g*8+h] = fmaxf(red[g*8+h], red[(g+s)*8+h]);
        __syncthreads();
    }
    if (t < 8) s_m[t] = red[t];
    __syncthreads();
    float mh = s_m[h], s_acc = 0.f;
    for (int l = g; l < nl; l += 32) {
        float e = __expf(s_sc[l*8 + h] - mh);
        s_sc[l*8 + h] = e;
        s_acc += e;
    }
    red[g*8 + h] = s_acc;
    __syncthreads();
    #pragma unroll
    for (int s = 16; s; s >>= 1) {
        if (g < s) red[g*8+h] += red[(g+s)*8+h];
        __syncthreads();
    }
    if (t < 8) {
        size_t o = ((size_t)(lc*64 + b)*8 + t)*2;
        Fms[o] = s_m[t]; Fms[o+1] = red[t];
    }
    // --- PV, depth-3 prefetch ring ---
    const int par = t >> 7, c = t & 127;
    float4 acc[8] = {};
    const size_t vstride = (size_t)2*64*512;
    const float* vp = vals + ((size_t)(l0 + par)*64 + b)*512 + c*4;
    float4 v0, v1, v2;
    if (par < nl)     v0 = CF4(vp);
    if (par + 2 < nl) v1 = CF4(vp + vstride);
    if (par + 4 < nl) v2 = CF4(vp + 2*vstride);
    for (int il = par; il < nl; il += 2) {
        float4 pa = CF4(&s_sc[il*8]);
        float4 pb = CF4(&s_sc[il*8 + 4]);
        acc[0].x += pa.x*v0.x; acc[0].y += pa.x*v0.y; acc[0].z += pa.x*v0.z; acc[0].w += pa.x*v0.w;
        acc[1].x += pa.y*v0.x; acc[1].y += pa.y*v0.y; acc[1].z += pa.y*v0.z; acc[1].w += pa.y*v0.w;
        acc[2].x += pa.z*v0.x; acc[2].y += pa.z*v0.y; acc[2].z += pa.z*v0.z; acc[2].w += pa.z*v0.w;
        acc[3].x += pa.w*v0.x; acc[3].y += pa.w*v0.y; acc[3].z += pa.w*v0.z; acc[3].w += pa.w*v0.w;
        acc[4].x += pb.x*v0.x; acc[4].y += pb.x*v0.y; acc[4].z += pb.x*v0.z; acc[4].w += pb.x*v0.w;
        acc[5].x += pb.y*v0.x; acc[5].y += pb.y*v0.y; acc[5].z += pb.y*v0.z; acc[5].w += pb.y*v0.w;
        acc[6].x += pb.z*v0.x; acc[6].y += pb.z*v0.y; acc[6].z += pb.z*v0.z; acc[6].w += pb.z*v0.w;
        acc[7].x += pb.w*v0.x; acc[7].y += pb.w*v0.y; acc[7].z += pb.w*v0.z; acc[7].w += pb.w*v0.w;
        v0 = v1; v1 = v2;
        if (il + 6 < nl) v2 = CF4(vp + 3*vstride);
        vp += vstride;
    }
    __syncthreads();
    if (par == 1) {
        #pragma unroll
        for (int hh = 0; hh < 8; ++hh)
            F4(&s_q[(c*8 + hh)*4]) = acc[hh];
    }
    __syncthreads();
    if (par == 0) {
        #pragma unroll
        for (int hh = 0; hh < 8; ++hh) {
            float4 o = CF4(&s_q[(c*8 + hh)*4]);
            o.x += acc[hh].x; o.y += acc[hh].y; o.z += acc[hh].z; o.w += acc[hh].w;
            F4(&facc_out[hh*512 + c*4]) = o;
        }
    }
}

// ============ k_comb: flash combine -> res[64][4096] ============
__global__ __launch_bounds__(256) void k_comb(
    const float* __restrict__ Facc, const float* __restrict__ Fms,
    float* __restrict__ res)
{
    __shared__ float wgt[16*8];
    const int b = blockIdx.x, t = threadIdx.x;
    if (t < 8) {
        float mm[16], ss[16], e[16];
        float M = -1e30f;
        #pragma unroll
        for (int i = 0; i < 16; ++i) {
            size_t o = ((size_t)(i*64 + b)*8 + t)*2;
            mm[i] = Fms[o]; ss[i] = Fms[o+1];
            M = fmaxf(M, mm[i]);
        }
        float D = 0.f;
        #pragma unroll
        for (int i = 0; i < 16; ++i) { e[i] = __expf(mm[i] - M); D += e[i]*ss[i]; }
        float invD = 1.f / D;
        #pragma unroll
        for (int i = 0; i < 16; ++i) wgt[i*8 + t] = e[i] * invD;
    }
    __syncthreads();
    #pragma unroll
    for (int j = 0; j < 4; ++j) {
        int f = t + j*256;
        int h = f >> 7;
        float4 a = {0.f, 0.f, 0.f, 0.f};
        #pragma unroll
        for (int i = 0; i < 16; ++i) {
            float wi = wgt[i*8 + h];
            float4 v = CF4(&Facc[((size_t)(i*64) + b)*4096 + f*4]);
            a.x += wi*v.x; a.y += wi*v.y; a.z += wi*v.z; a.w += wi*v.w;
        }
        F4(&res[(size_t)b*4096 + f*4]) = a;
    }
}

// ============ tail GEMMs ============
__global__ __launch_bounds__(256) void k_agg(
    const float* __restrict__ res, const float* __restrict__ Wagg,
    float* __restrict__ P5)
{
    const int nt = blockIdx.x, ks = blockIdx.y;     // 8 x 32
    gemm_core(res, nullptr, nullptr, 1, 4096, 128, ks*128,
              Wagg, 512, nt*64, nullptr, P5 + (size_t)ks*64*512, 512);
}

__global__ __launch_bounds__(256) void k_rkv1(
    const float* __restrict__ P5, const float* __restrict__ bagg,
    const float* __restrict__ Wrk1, const float* __restrict__ Wrv1,
    float* __restrict__ P6)
{
    const int nt = blockIdx.x, ks = blockIdx.y, z = blockIdx.z;  // 8 x 4 x 2
    gemm_core(P5, bagg, nullptr, 32, 512, 128, ks*128,
              z ? Wrv1 : Wrk1, 512, nt*64,
              nullptr, P6 + (size_t)(z*4 + ks)*64*512, 512);
}

__global__ __launch_bounds__(256) void k_rkv2(
    const float* __restrict__ P6,
    const float* __restrict__ brk1, const float* __restrict__ brv1,
    const float* __restrict__ Wrk2, const float* __restrict__ Wrv2,
    const float* __restrict__ brk2, const float* __restrict__ brv2,
    float* __restrict__ out)
{
    const int nt = blockIdx.x, z = blockIdx.z;      // 8 x 1 x 2
    gemm_core(P6 + (size_t)z*4*64*512, z ? brv1 : brk1, nullptr, 4, 512, 512, 0,
              z ? Wrv2 : Wrk2, 512, nt*64,
              z ? brv2 : brk2, out + (size_t)z*64*512, 512);
}

// ============ launch ============
extern "C" void kernel_launch(void* const* d_in, const int* in_sizes, int n_in,
                              void* d_out, int out_size, void* d_ws, size_t ws_size,
                              hipStream_t stream) {
    const float* state   = (const float*)d_in[0];
    const float* til     = (const float*)d_in[1];
    const float* keys    = (const float*)d_in[2];
    const float* vals    = (const float*)d_in[3];
    const float* rpe     = (const float*)d_in[4];
    const int*   step    = (const int*)d_in[5];
    const float* W_state = (const float*)d_in[6];
    const float* b_state = (const float*)d_in[7];
    const float* Wcq1 = (const float*)d_in[8];
    const float* bcq1 = (const float*)d_in[9];
    const float* Wcq2 = (const float*)d_in[10];
    const float* bcq2 = (const float*)d_in[11];
    const float* Wq   = (const float*)d_in[12];
    const float* bq   = (const float*)d_in[13];
    const float* Wagg = (const float*)d_in[14];
    const float* bagg = (const float*)d_in[15];
    const float* Wrk1 = (const float*)d_in[16];
    const float* brk1 = (const float*)d_in[17];
    const float* Wrk2 = (const float*)d_in[18];
    const float* brk2 = (const float*)d_in[19];
    const float* Wrv1 = (const float*)d_in[20];
    const float* brv1 = (const float*)d_in[21];
    const float* Wrv2 = (const float*)d_in[22];
    const float* brv2 = (const float*)d_in[23];
    float* out = (float*)d_out;
    float* ws  = (float*)d_ws;

    float* P1   = ws;              // [8][64][256]   131072  dead after k_q2
    float* P2   = ws + 131072;     // [8][64][512]   262144  dead after k_q3
    float* P3   = ws + 393216;     // [8][64][512]   262144  dead after k_qh
    float* P4   = ws + 655360;     // [4][64][4096]  1048576 dead after k_qsum
    float* qh   = ws + 1703936;    // [64][4096]     262144
    float* Facc = ws + 1966080;    // [16][64][4096] 4194304
    float* Fms  = ws + 6160384;    // 16*64*8*2      16384
    float* res  = ws + 6176768;    // [64][4096]     262144
    float* P5   = ws;              // [32][64][512]  1048576 (reuses P1..P4)
    float* P6   = ws + 1048576;    // [2][4][64][512] 262144 (reuses P4 tail)

    k_q1  <<<dim3(4,8),   256, 0, stream>>>(state, W_state, P1);
    k_q2  <<<dim3(8,8),   256, 0, stream>>>(P1, b_state, til, Wcq1, P2);
    k_q3  <<<dim3(8,8),   256, 0, stream>>>(P2, bcq1, Wcq2, P3);
    k_qh  <<<dim3(64,4),  256, 0, stream>>>(P3, bcq2, Wq, P4);
    k_qsum<<<64, 256, 0, stream>>>(P4, bq, qh);
    k_fa  <<<dim3(16,64), 256, 0, stream>>>(keys, rpe, qh, vals, step, Facc, Fms);
    k_comb<<<64, 256, 0, stream>>>(Facc, Fms, res);
    k_agg <<<dim3(8,32),  256, 0, stream>>>(res, Wagg, P5);
    k_rkv1<<<dim3(8,4,2), 256, 0, stream>>>(P5, bagg, Wrk1, Wrv1, P6);
    k_rkv2<<<dim3(8,1,2), 256, 0, stream>>>(P6, brk1, brv1, Wrk2, Wrv2,
                                            brk2, brv2, out);
}